// Round 3
// baseline (616.506 us; speedup 1.0000x reference)
//
#include <hip/hip_runtime.h>
#include <hip/hip_bf16.h>

#define C_DIM 1024
#define H_DIM 512
#define V_DIM 32000
#define B_DIM 16
#define T_DIM 256
#define SPW   8

// ---------------- generic small GEMM: out = act(A@B^T + bias) (+resid) ----------
// A: M x K f32, B: N x K f32. flags bit0 = relu.
__global__ __launch_bounds__(256) void gemm_kern(
    const float* __restrict__ A, const float* __restrict__ B,
    const float* __restrict__ bias, const float* __restrict__ resid,
    float* __restrict__ out, int M, int N, int K, int flags)
{
    __shared__ __align__(16) float As[16][64];
    __shared__ __align__(16) float Bs[16][64];
    int tid = threadIdx.x;
    int m0 = blockIdx.x * 64, n0 = blockIdx.y * 64;
    int ty = tid >> 4, tx = tid & 15;
    int lr = tid >> 2;          // 0..63 row within tile
    int lk = (tid & 3) << 2;    // 0,4,8,12 k offset
    float acc[4][4] = {};
    for (int k0 = 0; k0 < K; k0 += 16) {
        float4 av = *(const float4*)(A + (size_t)(m0 + lr) * K + k0 + lk);
        float4 bv = *(const float4*)(B + (size_t)(n0 + lr) * K + k0 + lk);
        __syncthreads();
        As[lk + 0][lr] = av.x; As[lk + 1][lr] = av.y;
        As[lk + 2][lr] = av.z; As[lk + 3][lr] = av.w;
        Bs[lk + 0][lr] = bv.x; Bs[lk + 1][lr] = bv.y;
        Bs[lk + 2][lr] = bv.z; Bs[lk + 3][lr] = bv.w;
        __syncthreads();
#pragma unroll
        for (int kk = 0; kk < 16; kk++) {
            float4 a = *(const float4*)&As[kk][ty << 2];
            float4 b = *(const float4*)&Bs[kk][tx << 2];
            acc[0][0] += a.x * b.x; acc[0][1] += a.x * b.y; acc[0][2] += a.x * b.z; acc[0][3] += a.x * b.w;
            acc[1][0] += a.y * b.x; acc[1][1] += a.y * b.y; acc[1][2] += a.y * b.z; acc[1][3] += a.y * b.w;
            acc[2][0] += a.z * b.x; acc[2][1] += a.z * b.y; acc[2][2] += a.z * b.z; acc[2][3] += a.z * b.w;
            acc[3][0] += a.w * b.x; acc[3][1] += a.w * b.y; acc[3][2] += a.w * b.z; acc[3][3] += a.w * b.w;
        }
    }
#pragma unroll
    for (int r = 0; r < 4; r++) {
        int m = m0 + (ty << 2) + r;
#pragma unroll
        for (int c = 0; c < 4; c++) {
            int n = n0 + (tx << 2) + c;
            float v = acc[r][c];
            if (bias) v += bias[n];
            if (flags & 1) v = fmaxf(v, 0.0f);
            if (resid) v += resid[(size_t)m * N + n];
            out[(size_t)m * N + n] = v;
        }
    }
}

// ---------------- start head: logits + log_softmax over C (single block) --------
__global__ __launch_bounds__(1024) void start_kern(
    const float* __restrict__ Rstart, const float* __restrict__ sow,
    const float* __restrict__ sob, float* __restrict__ start)
{
    int c = threadIdx.x;
    const float4* rp = (const float4*)(Rstart + (size_t)c * H_DIM);
    const float4* wp = (const float4*)(sow);
    float d = 0.0f;
    for (int k = 0; k < H_DIM / 4; k++) {
        float4 r = rp[k], w = wp[k];
        d += r.x * w.x + r.y * w.y + r.z * w.z + r.w * w.w;
    }
    d += sob[0];
    __shared__ float red[1024];
    red[c] = expf(d);           // |d| < ~1, unstable-safe
    __syncthreads();
    for (int st = 512; st > 0; st >>= 1) {
        if (c < st) red[c] += red[c + st];
        __syncthreads();
    }
    __shared__ float lz;
    if (c == 0) lz = logf(red[0]);
    __syncthreads();
    start[c] = d - lz;
}

// ---------------- row log_softmax in place on TL (1024 x N f32) -----------------
__global__ __launch_bounds__(256) void rowsm_kern(float* __restrict__ TL, int N)
{
    int row = blockIdx.x, tid = threadIdx.x;
    float* p = TL + (size_t)row * N;
    float s = 0.0f;
    for (int j = tid; j < N; j += 256) s += expf(p[j]);   // |logit| < ~1
    __shared__ float red[256];
    red[tid] = s;
    __syncthreads();
    for (int st = 128; st > 0; st >>= 1) {
        if (tid < st) red[tid] += red[tid + st];
        __syncthreads();
    }
    __shared__ float lz;
    if (tid == 0) lz = logf(red[0]);
    __syncthreads();
    for (int j = tid; j < N; j += 256) p[j] -= lz;
}

// ---------------- zero accumulators ---------------------------------------------
__global__ void init_kern(float* __restrict__ Zsum, float* __restrict__ evid)
{
    int t = threadIdx.x;
    Zsum[t] = 0.0f;
    if (t == 0) *evid = 0.0f;
}

// ---------------- emission denominator: one wave per word -----------------------
__global__ __launch_bounds__(256) void zsum_kern(
    const float* __restrict__ Rterm, const float* __restrict__ tow,
    const float* __restrict__ tob, const int* __restrict__ w2s,
    float* __restrict__ Zsum)
{
    int wid = threadIdx.x >> 6, lane = threadIdx.x & 63;
    int v = blockIdx.x * 4 + wid;
    if (v >= V_DIM) return;
    const float4* twp = (const float4*)(tow + (size_t)v * H_DIM);
    float4 tw0 = twp[lane * 2], tw1 = twp[lane * 2 + 1];
    float ob = tob[v];
    int cs[SPW];
#pragma unroll
    for (int s = 0; s < SPW; s++) cs[s] = w2s[v * SPW + s];
#pragma unroll
    for (int s = 0; s < SPW; s++) {
        int c = cs[s];
        bool dup = false;
        for (int s2 = 0; s2 < s; s2++) dup = dup || (cs[s2] == c);
        if (dup) continue;   // wave-uniform branch (mask dedupes within a word)
        const float4* rp = (const float4*)(Rterm + (size_t)c * H_DIM);
        float4 r0 = rp[lane * 2], r1 = rp[lane * 2 + 1];
        float d = tw0.x * r0.x + tw0.y * r0.y + tw0.z * r0.z + tw0.w * r0.w
                + tw1.x * r1.x + tw1.y * r1.y + tw1.z * r1.z + tw1.w * r1.w;
        for (int off = 1; off < 64; off <<= 1) d += __shfl_xor(d, off, 64);
        if (lane == 0) atomicAdd(Zsum + c, expf(d + ob));
    }
}

// ---------------- obs[b,t,s] = term_logit - log Zsum ----------------------------
__global__ __launch_bounds__(256) void obs_kern(
    const float* __restrict__ Rterm, const float* __restrict__ tow,
    const float* __restrict__ tob, const int* __restrict__ w2s,
    const int* __restrict__ text, const float* __restrict__ Zsum,
    float* __restrict__ obs)
{
    int wid = threadIdx.x >> 6, lane = threadIdx.x & 63;
    int idx = blockIdx.x * 4 + wid;          // 0 .. B*T-1
    if (idx >= B_DIM * T_DIM) return;
    int v = text[idx];
    const float4* twp = (const float4*)(tow + (size_t)v * H_DIM);
    float4 tw0 = twp[lane * 2], tw1 = twp[lane * 2 + 1];
    float ob = tob[v];
#pragma unroll
    for (int s = 0; s < SPW; s++) {
        int c = w2s[v * SPW + s];
        const float4* rp = (const float4*)(Rterm + (size_t)c * H_DIM);
        float4 r0 = rp[lane * 2], r1 = rp[lane * 2 + 1];
        float d = tw0.x * r0.x + tw0.y * r0.y + tw0.z * r0.z + tw0.w * r0.w
                + tw1.x * r1.x + tw1.y * r1.y + tw1.z * r1.z + tw1.w * r1.w;
        for (int off = 1; off < 64; off <<= 1) d += __shfl_xor(d, off, 64);
        if (lane == 0) obs[idx * SPW + s] = d + ob - logf(Zsum[c]);
    }
}

// ---------------- potential gather: P[b][t][j*8+i] ------------------------------
__global__ __launch_bounds__(64) void pot_kern(
    const float* __restrict__ trans, const float* __restrict__ obs,
    const float* __restrict__ start, const int* __restrict__ text,
    const int* __restrict__ w2s, float* __restrict__ P)
{
    int bt = blockIdx.x;                  // 0 .. B*(T-1)-1
    int b = bt / (T_DIM - 1), t = bt % (T_DIM - 1);
    int lane = threadIdx.x;
    int j = lane >> 3, i = lane & 7;
    int vt  = text[b * T_DIM + t];
    int vt1 = text[b * T_DIM + t + 1];
    int ci = w2s[vt * SPW + i];
    int cj = w2s[vt1 * SPW + j];
    float p = trans[(size_t)ci * C_DIM + cj] + obs[(b * T_DIM + t + 1) * SPW + j];
    if (t == 0) p += start[ci] + obs[(b * T_DIM) * SPW + i];
    P[(size_t)bt * 64 + lane] = p;
}

// ---------------- forward scan: one wave per batch ------------------------------
__global__ __launch_bounds__(64) void scan_kern(const float* __restrict__ P,
                                                float* __restrict__ evid)
{
    int b = blockIdx.x, lane = threadIdx.x;
    const float* base = P + (size_t)b * (T_DIM - 1) * 64;
    float A = 0.0f, off = 0.0f;          // alpha_hat[j] (replicated in group j), running offset
    float pc = base[lane];
    for (int t = 0; t < T_DIM - 1; t++) {
        float pn = (t < T_DIM - 2) ? base[(size_t)(t + 1) * 64 + lane] : 0.0f;
        float av = __shfl(A, (lane & 7) << 3, 64);   // alpha_hat[i]
        float x = pc + av;
        float m = x;
        m = fmaxf(m, __shfl_xor(m, 1, 64));
        m = fmaxf(m, __shfl_xor(m, 2, 64));
        m = fmaxf(m, __shfl_xor(m, 4, 64));
        float e = expf(x - m);
        e += __shfl_xor(e, 1, 64);
        e += __shfl_xor(e, 2, 64);
        e += __shfl_xor(e, 4, 64);
        float aj = m + logf(e);
        float g = aj;
        g = fmaxf(g, __shfl_xor(g, 8, 64));
        g = fmaxf(g, __shfl_xor(g, 16, 64));
        g = fmaxf(g, __shfl_xor(g, 32, 64));
        A = aj - g;
        off += g;
        pc = pn;
    }
    float ev = ((lane & 7) == 0) ? expf(A) : 0.0f;
    for (int o = 1; o < 64; o <<= 1) ev += __shfl_xor(ev, o, 64);
    if (lane == 0) atomicAdd(evid, off + logf(ev));
}

// ---------------- final scalar write (f32 out) ----------------------------------
__global__ void out_kern(const float* __restrict__ evid, float* __restrict__ out)
{
    if (threadIdx.x == 0) out[0] = *evid;
}

extern "C" void kernel_launch(void* const* d_in, const int* in_sizes, int n_in,
                              void* d_out, int out_size, void* d_ws, size_t ws_size,
                              hipStream_t stream)
{
    const float* start_emb = (const float*)d_in[0];
    const float* start_l1w = (const float*)d_in[1];
    const float* start_l1b = (const float*)d_in[2];
    const float* start_l2w = (const float*)d_in[3];
    const float* start_l2b = (const float*)d_in[4];
    const float* start_ow  = (const float*)d_in[5];
    const float* start_ob  = (const float*)d_in[6];
    const float* state_emb = (const float*)d_in[7];
    const float* trans_l1w = (const float*)d_in[8];
    const float* trans_l1b = (const float*)d_in[9];
    const float* trans_l2w = (const float*)d_in[10];
    const float* trans_l2b = (const float*)d_in[11];
    const float* proj_w    = (const float*)d_in[12];
    const float* pret_emb  = (const float*)d_in[13];
    const float* term_l1w  = (const float*)d_in[14];
    const float* term_l1b  = (const float*)d_in[15];
    const float* term_l2w  = (const float*)d_in[16];
    const float* term_l2b  = (const float*)d_in[17];
    const float* term_ow   = (const float*)d_in[18];
    const float* term_ob   = (const float*)d_in[19];
    const int*   text      = (const int*)d_in[20];
    const int*   w2s       = (const int*)d_in[21];

    char* w = (char*)d_ws;
    float* Hbuf   = (float*)(w);                            // 2 MB
    float* Rstart = (float*)(w + 2u * (1u << 20));          // 2 MB
    float* Rtrans = (float*)(w + 4u * (1u << 20));          // 2 MB
    float* Rterm  = (float*)(w + 6u * (1u << 20));          // 2 MB
    float* TL     = (float*)(w + 8u * (1u << 20));          // 4 MB
    float* startv = (float*)(w + 12u * (1u << 20));         // 4 KB
    float* Zsum   = (float*)(w + 12u * (1u << 20) + 8192);  // 4 KB
    float* obs    = (float*)(w + 12u * (1u << 20) + 16384); // 128 KB
    float* P      = (float*)(w + 12u * (1u << 20) + 16384 + 131072);   // ~1 MB
    float* evid   = (float*)(w + 12u * (1u << 20) + 16384 + 131072 + 1048576);

    dim3 blk256(256), blk64(64);

    init_kern<<<1, 1024, 0, stream>>>(Zsum, evid);

    // 3 residual MLPs (weights are (out,in) -> B operand of A@B^T)
    gemm_kern<<<dim3(16, 8), blk256, 0, stream>>>(start_emb, start_l1w, start_l1b, nullptr,
                                                  Hbuf, C_DIM, H_DIM, H_DIM, 1);
    gemm_kern<<<dim3(16, 8), blk256, 0, stream>>>(Hbuf, start_l2w, start_l2b, start_emb,
                                                  Rstart, C_DIM, H_DIM, H_DIM, 1);
    gemm_kern<<<dim3(16, 8), blk256, 0, stream>>>(state_emb, trans_l1w, trans_l1b, nullptr,
                                                  Hbuf, C_DIM, H_DIM, H_DIM, 1);
    gemm_kern<<<dim3(16, 8), blk256, 0, stream>>>(Hbuf, trans_l2w, trans_l2b, state_emb,
                                                  Rtrans, C_DIM, H_DIM, H_DIM, 1);
    gemm_kern<<<dim3(16, 8), blk256, 0, stream>>>(pret_emb, term_l1w, term_l1b, nullptr,
                                                  Hbuf, C_DIM, H_DIM, H_DIM, 1);
    gemm_kern<<<dim3(16, 8), blk256, 0, stream>>>(Hbuf, term_l2w, term_l2b, pret_emb,
                                                  Rterm, C_DIM, H_DIM, H_DIM, 1);
    // trans logits
    gemm_kern<<<dim3(16, 16), blk256, 0, stream>>>(Rtrans, proj_w, nullptr, nullptr,
                                                   TL, C_DIM, C_DIM, H_DIM, 0);

    start_kern<<<1, 1024, 0, stream>>>(Rstart, start_ow, start_ob, startv);
    rowsm_kern<<<C_DIM, blk256, 0, stream>>>(TL, C_DIM);

    zsum_kern<<<V_DIM / 4, blk256, 0, stream>>>(Rterm, term_ow, term_ob, w2s, Zsum);
    obs_kern<<<B_DIM * T_DIM / 4, blk256, 0, stream>>>(Rterm, term_ow, term_ob, w2s,
                                                       text, Zsum, obs);
    pot_kern<<<B_DIM * (T_DIM - 1), blk64, 0, stream>>>(TL, obs, startv, text, w2s, P);
    scan_kern<<<B_DIM, blk64, 0, stream>>>(P, evid);
    out_kern<<<1, 64, 0, stream>>>(evid, (float*)d_out);
}

// Round 4
// 540.326 us; speedup vs baseline: 1.1410x; 1.1410x over previous
//
#include <hip/hip_runtime.h>
#include <hip/hip_bf16.h>

#define C_DIM 1024
#define H_DIM 512
#define V_DIM 32000
#define B_DIM 16
#define T_DIM 256
#define SPW   8

typedef unsigned short u16;
typedef unsigned int   u32;
typedef __attribute__((ext_vector_type(8))) short bf16x8;
typedef __attribute__((ext_vector_type(4))) float f32x4;

__device__ __forceinline__ u16 f2b(float f) {
    union { float f; u32 i; } x; x.f = f;
    u32 i = x.i;
    i += 0x7fffu + ((i >> 16) & 1u);   // RNE
    return (u16)(i >> 16);
}
__device__ __forceinline__ u32 pk2(float a, float b) {
    return (u32)f2b(a) | ((u32)f2b(b) << 16);
}

// ---------------- MFMA GEMM: out = act(A@B^T + bias) (+resid), f32 in/out -------
// A: M x K f32, B: N x K f32. Internally bf16 MFMA. flags bit0 = relu.
// Tile 64x64, BK=32, 4 waves each owning a 32x32 quadrant (2x2 16x16 frags).
__global__ __launch_bounds__(256) void gemm_kern(
    const float* __restrict__ A, const float* __restrict__ B,
    const float* __restrict__ bias, const float* __restrict__ resid,
    float* __restrict__ out, int M, int N, int K, int flags)
{
    __shared__ __align__(16) u16 As[64][40];   // 32 data + 8 pad (80B stride, 16B aligned)
    __shared__ __align__(16) u16 Bs[64][40];
    int tid  = threadIdx.x;
    int m0 = blockIdx.x * 64, n0 = blockIdx.y * 64;
    int wave = tid >> 6, lane = tid & 63;
    int wr = wave >> 1, wc = wave & 1;          // quadrant row/col
    int srow = tid >> 2, scol = (tid & 3) << 3; // staging: row 0..63, col-seg 0/8/16/24
    int quad = lane >> 4, l16 = lane & 15;
    f32x4 acc[2][2] = {};

    for (int k0 = 0; k0 < K; k0 += 32) {
        const float4* ap = (const float4*)(A + (size_t)(m0 + srow) * K + k0 + scol);
        const float4* bp = (const float4*)(B + (size_t)(n0 + srow) * K + k0 + scol);
        float4 a0 = ap[0], a1 = ap[1];
        float4 b0 = bp[0], b1 = bp[1];
        __syncthreads();   // previous iter's LDS reads done
        uint4 pa, pb;
        pa.x = pk2(a0.x, a0.y); pa.y = pk2(a0.z, a0.w);
        pa.z = pk2(a1.x, a1.y); pa.w = pk2(a1.z, a1.w);
        pb.x = pk2(b0.x, b0.y); pb.y = pk2(b0.z, b0.w);
        pb.z = pk2(b1.x, b1.y); pb.w = pk2(b1.z, b1.w);
        *(uint4*)&As[srow][scol] = pa;
        *(uint4*)&Bs[srow][scol] = pb;
        __syncthreads();
        bf16x8 af0 = *(const bf16x8*)&As[wr * 32 + l16][quad * 8];
        bf16x8 af1 = *(const bf16x8*)&As[wr * 32 + 16 + l16][quad * 8];
        bf16x8 bf0 = *(const bf16x8*)&Bs[wc * 32 + l16][quad * 8];
        bf16x8 bf1 = *(const bf16x8*)&Bs[wc * 32 + 16 + l16][quad * 8];
        acc[0][0] = __builtin_amdgcn_mfma_f32_16x16x32_bf16(af0, bf0, acc[0][0], 0, 0, 0);
        acc[0][1] = __builtin_amdgcn_mfma_f32_16x16x32_bf16(af0, bf1, acc[0][1], 0, 0, 0);
        acc[1][0] = __builtin_amdgcn_mfma_f32_16x16x32_bf16(af1, bf0, acc[1][0], 0, 0, 0);
        acc[1][1] = __builtin_amdgcn_mfma_f32_16x16x32_bf16(af1, bf1, acc[1][1], 0, 0, 0);
    }
#pragma unroll
    for (int sm = 0; sm < 2; sm++)
#pragma unroll
        for (int sn = 0; sn < 2; sn++) {
            int n = n0 + wc * 32 + sn * 16 + l16;
            float bv = bias ? bias[n] : 0.0f;
#pragma unroll
            for (int reg = 0; reg < 4; reg++) {
                int m = m0 + wr * 32 + sm * 16 + quad * 4 + reg;
                float v = acc[sm][sn][reg] + bv;
                if (flags & 1) v = fmaxf(v, 0.0f);
                if (resid) v += resid[(size_t)m * N + n];
                out[(size_t)m * N + n] = v;
            }
        }
}

// ---------------- start head: logits + log_softmax over C (single block) --------
__global__ __launch_bounds__(1024) void start_kern(
    const float* __restrict__ Rstart, const float* __restrict__ sow,
    const float* __restrict__ sob, float* __restrict__ start)
{
    int c = threadIdx.x;
    const float4* rp = (const float4*)(Rstart + (size_t)c * H_DIM);
    const float4* wp = (const float4*)(sow);
    float d = 0.0f;
    for (int k = 0; k < H_DIM / 4; k++) {
        float4 r = rp[k], w = wp[k];
        d += r.x * w.x + r.y * w.y + r.z * w.z + r.w * w.w;
    }
    d += sob[0];
    __shared__ float red[1024];
    red[c] = expf(d);
    __syncthreads();
    for (int st = 512; st > 0; st >>= 1) {
        if (c < st) red[c] += red[c + st];
        __syncthreads();
    }
    __shared__ float lz;
    if (c == 0) lz = logf(red[0]);
    __syncthreads();
    start[c] = d - lz;
}

// ---------------- row log_softmax in place on TL (1024 x N f32) -----------------
__global__ __launch_bounds__(256) void rowsm_kern(float* __restrict__ TL, int N)
{
    int row = blockIdx.x, tid = threadIdx.x;
    float* p = TL + (size_t)row * N;
    float s = 0.0f;
    for (int j = tid; j < N; j += 256) s += expf(p[j]);
    __shared__ float red[256];
    red[tid] = s;
    __syncthreads();
    for (int st = 128; st > 0; st >>= 1) {
        if (tid < st) red[tid] += red[tid + st];
        __syncthreads();
    }
    __shared__ float lz;
    if (tid == 0) lz = logf(red[0]);
    __syncthreads();
    for (int j = tid; j < N; j += 256) p[j] -= lz;
}

// ---------------- zero accumulators ---------------------------------------------
__global__ void init_kern(float* __restrict__ Zsum, float* __restrict__ evid)
{
    int t = threadIdx.x;
    Zsum[t] = 0.0f;
    if (t == 0) *evid = 0.0f;
}

// ---------------- emission denominator: one wave per word, full prefetch --------
__global__ __launch_bounds__(256) void zsum_kern(
    const float* __restrict__ Rterm, const float* __restrict__ tow,
    const float* __restrict__ tob, const int* __restrict__ w2s,
    float* __restrict__ Zsum)
{
    int wid = threadIdx.x >> 6, lane = threadIdx.x & 63;
    int v = blockIdx.x * 4 + wid;
    const float4* twp = (const float4*)(tow + (size_t)v * H_DIM);
    float4 tw0 = twp[lane * 2], tw1 = twp[lane * 2 + 1];
    float ob = tob[v];
    int cs[SPW];
#pragma unroll
    for (int s = 0; s < SPW; s++) cs[s] = w2s[v * SPW + s];
    // issue ALL row loads before any use
    float4 r0[SPW], r1[SPW];
#pragma unroll
    for (int s = 0; s < SPW; s++) {
        const float4* rp = (const float4*)(Rterm + (size_t)cs[s] * H_DIM);
        r0[s] = rp[lane * 2]; r1[s] = rp[lane * 2 + 1];
    }
    float d[SPW];
#pragma unroll
    for (int s = 0; s < SPW; s++) {
        d[s] = tw0.x * r0[s].x + tw0.y * r0[s].y + tw0.z * r0[s].z + tw0.w * r0[s].w
             + tw1.x * r1[s].x + tw1.y * r1[s].y + tw1.z * r1[s].z + tw1.w * r1[s].w;
        d[s] += __shfl_xor(d[s], 1, 64);
        d[s] += __shfl_xor(d[s], 2, 64);
        d[s] += __shfl_xor(d[s], 4, 64);
    }
    // lane picks its state's group-partial, then cross-group butterfly
    float x = d[0];
    int myc = cs[0];
#pragma unroll
    for (int s = 1; s < SPW; s++) {
        if ((lane & 7) == s) { x = d[s]; myc = cs[s]; }
    }
    x += __shfl_xor(x, 8, 64);
    x += __shfl_xor(x, 16, 64);
    x += __shfl_xor(x, 32, 64);
    // dedupe mask (computed uniformly on all lanes)
    u32 dupmask = 0;
#pragma unroll
    for (int s = 1; s < SPW; s++) {
        bool dp = false;
#pragma unroll
        for (int s2 = 0; s2 < s; s2++) dp = dp || (cs[s2] == cs[s]);
        if (dp) dupmask |= (1u << s);
    }
    if (lane < 8 && !((dupmask >> lane) & 1u))
        atomicAdd(Zsum + myc, expf(x + ob));
}

// ---------------- obs[b,t,s] = term_logit - log Zsum, full prefetch -------------
__global__ __launch_bounds__(256) void obs_kern(
    const float* __restrict__ Rterm, const float* __restrict__ tow,
    const float* __restrict__ tob, const int* __restrict__ w2s,
    const int* __restrict__ text, const float* __restrict__ Zsum,
    float* __restrict__ obs)
{
    int wid = threadIdx.x >> 6, lane = threadIdx.x & 63;
    int idx = blockIdx.x * 4 + wid;          // 0 .. B*T-1
    int v = text[idx];
    const float4* twp = (const float4*)(tow + (size_t)v * H_DIM);
    float4 tw0 = twp[lane * 2], tw1 = twp[lane * 2 + 1];
    float ob = tob[v];
    int cs[SPW];
#pragma unroll
    for (int s = 0; s < SPW; s++) cs[s] = w2s[v * SPW + s];
    float4 r0[SPW], r1[SPW];
#pragma unroll
    for (int s = 0; s < SPW; s++) {
        const float4* rp = (const float4*)(Rterm + (size_t)cs[s] * H_DIM);
        r0[s] = rp[lane * 2]; r1[s] = rp[lane * 2 + 1];
    }
    float d[SPW];
#pragma unroll
    for (int s = 0; s < SPW; s++) {
        d[s] = tw0.x * r0[s].x + tw0.y * r0[s].y + tw0.z * r0[s].z + tw0.w * r0[s].w
             + tw1.x * r1[s].x + tw1.y * r1[s].y + tw1.z * r1[s].z + tw1.w * r1[s].w;
        d[s] += __shfl_xor(d[s], 1, 64);
        d[s] += __shfl_xor(d[s], 2, 64);
        d[s] += __shfl_xor(d[s], 4, 64);
    }
    float x = d[0];
    int myc = cs[0];
#pragma unroll
    for (int s = 1; s < SPW; s++) {
        if ((lane & 7) == s) { x = d[s]; myc = cs[s]; }
    }
    x += __shfl_xor(x, 8, 64);
    x += __shfl_xor(x, 16, 64);
    x += __shfl_xor(x, 32, 64);
    if (lane < 8)
        obs[idx * SPW + lane] = x + ob - logf(Zsum[myc]);
}

// ---------------- potential gather: P[b][t][j*8+i] ------------------------------
__global__ __launch_bounds__(64) void pot_kern(
    const float* __restrict__ trans, const float* __restrict__ obs,
    const float* __restrict__ start, const int* __restrict__ text,
    const int* __restrict__ w2s, float* __restrict__ P)
{
    int bt = blockIdx.x;                  // 0 .. B*(T-1)-1
    int b = bt / (T_DIM - 1), t = bt % (T_DIM - 1);
    int lane = threadIdx.x;
    int j = lane >> 3, i = lane & 7;
    int vt  = text[b * T_DIM + t];
    int vt1 = text[b * T_DIM + t + 1];
    int ci = w2s[vt * SPW + i];
    int cj = w2s[vt1 * SPW + j];
    float p = trans[(size_t)ci * C_DIM + cj] + obs[(b * T_DIM + t + 1) * SPW + j];
    if (t == 0) p += start[ci] + obs[(b * T_DIM) * SPW + i];
    P[(size_t)bt * 64 + lane] = p;
}

// ---------------- forward scan: one wave per batch ------------------------------
__global__ __launch_bounds__(64) void scan_kern(const float* __restrict__ P,
                                                float* __restrict__ evid)
{
    int b = blockIdx.x, lane = threadIdx.x;
    const float* base = P + (size_t)b * (T_DIM - 1) * 64;
    float A = 0.0f, off = 0.0f;
    float pc = base[lane];
    for (int t = 0; t < T_DIM - 1; t++) {
        float pn = (t < T_DIM - 2) ? base[(size_t)(t + 1) * 64 + lane] : 0.0f;
        float av = __shfl(A, (lane & 7) << 3, 64);
        float x = pc + av;
        float m = x;
        m = fmaxf(m, __shfl_xor(m, 1, 64));
        m = fmaxf(m, __shfl_xor(m, 2, 64));
        m = fmaxf(m, __shfl_xor(m, 4, 64));
        float e = expf(x - m);
        e += __shfl_xor(e, 1, 64);
        e += __shfl_xor(e, 2, 64);
        e += __shfl_xor(e, 4, 64);
        float aj = m + logf(e);
        float g = aj;
        g = fmaxf(g, __shfl_xor(g, 8, 64));
        g = fmaxf(g, __shfl_xor(g, 16, 64));
        g = fmaxf(g, __shfl_xor(g, 32, 64));
        A = aj - g;
        off += g;
        pc = pn;
    }
    float ev = ((lane & 7) == 0) ? expf(A) : 0.0f;
    for (int o = 1; o < 64; o <<= 1) ev += __shfl_xor(ev, o, 64);
    if (lane == 0) atomicAdd(evid, off + logf(ev));
}

// ---------------- final scalar write (f32 out) ----------------------------------
__global__ void out_kern(const float* __restrict__ evid, float* __restrict__ out)
{
    if (threadIdx.x == 0) out[0] = *evid;
}

extern "C" void kernel_launch(void* const* d_in, const int* in_sizes, int n_in,
                              void* d_out, int out_size, void* d_ws, size_t ws_size,
                              hipStream_t stream)
{
    const float* start_emb = (const float*)d_in[0];
    const float* start_l1w = (const float*)d_in[1];
    const float* start_l1b = (const float*)d_in[2];
    const float* start_l2w = (const float*)d_in[3];
    const float* start_l2b = (const float*)d_in[4];
    const float* start_ow  = (const float*)d_in[5];
    const float* start_ob  = (const float*)d_in[6];
    const float* state_emb = (const float*)d_in[7];
    const float* trans_l1w = (const float*)d_in[8];
    const float* trans_l1b = (const float*)d_in[9];
    const float* trans_l2w = (const float*)d_in[10];
    const float* trans_l2b = (const float*)d_in[11];
    const float* proj_w    = (const float*)d_in[12];
    const float* pret_emb  = (const float*)d_in[13];
    const float* term_l1w  = (const float*)d_in[14];
    const float* term_l1b  = (const float*)d_in[15];
    const float* term_l2w  = (const float*)d_in[16];
    const float* term_l2b  = (const float*)d_in[17];
    const float* term_ow   = (const float*)d_in[18];
    const float* term_ob   = (const float*)d_in[19];
    const int*   text      = (const int*)d_in[20];
    const int*   w2s       = (const int*)d_in[21];

    char* w = (char*)d_ws;
    float* Hbuf   = (float*)(w);                            // 2 MB
    float* Rstart = (float*)(w + 2u * (1u << 20));          // 2 MB
    float* Rtrans = (float*)(w + 4u * (1u << 20));          // 2 MB
    float* Rterm  = (float*)(w + 6u * (1u << 20));          // 2 MB
    float* TL     = (float*)(w + 8u * (1u << 20));          // 4 MB
    float* startv = (float*)(w + 12u * (1u << 20));         // 4 KB
    float* Zsum   = (float*)(w + 12u * (1u << 20) + 8192);  // 4 KB
    float* obs    = (float*)(w + 12u * (1u << 20) + 16384); // 128 KB
    float* P      = (float*)(w + 12u * (1u << 20) + 16384 + 131072);   // ~1 MB
    float* evid   = (float*)(w + 12u * (1u << 20) + 16384 + 131072 + 1048576);

    dim3 blk256(256), blk64(64);

    init_kern<<<1, 1024, 0, stream>>>(Zsum, evid);

    // 3 residual MLPs (weights are (out,in) -> B operand of A@B^T), bf16 MFMA
    gemm_kern<<<dim3(16, 8), blk256, 0, stream>>>(start_emb, start_l1w, start_l1b, nullptr,
                                                  Hbuf, C_DIM, H_DIM, H_DIM, 1);
    gemm_kern<<<dim3(16, 8), blk256, 0, stream>>>(Hbuf, start_l2w, start_l2b, start_emb,
                                                  Rstart, C_DIM, H_DIM, H_DIM, 1);
    gemm_kern<<<dim3(16, 8), blk256, 0, stream>>>(state_emb, trans_l1w, trans_l1b, nullptr,
                                                  Hbuf, C_DIM, H_DIM, H_DIM, 1);
    gemm_kern<<<dim3(16, 8), blk256, 0, stream>>>(Hbuf, trans_l2w, trans_l2b, state_emb,
                                                  Rtrans, C_DIM, H_DIM, H_DIM, 1);
    gemm_kern<<<dim3(16, 8), blk256, 0, stream>>>(pret_emb, term_l1w, term_l1b, nullptr,
                                                  Hbuf, C_DIM, H_DIM, H_DIM, 1);
    gemm_kern<<<dim3(16, 8), blk256, 0, stream>>>(Hbuf, term_l2w, term_l2b, pret_emb,
                                                  Rterm, C_DIM, H_DIM, H_DIM, 1);
    // trans logits
    gemm_kern<<<dim3(16, 16), blk256, 0, stream>>>(Rtrans, proj_w, nullptr, nullptr,
                                                   TL, C_DIM, C_DIM, H_DIM, 0);

    start_kern<<<1, 1024, 0, stream>>>(Rstart, start_ow, start_ob, startv);
    rowsm_kern<<<C_DIM, blk256, 0, stream>>>(TL, C_DIM);

    zsum_kern<<<V_DIM / 4, blk256, 0, stream>>>(Rterm, term_ow, term_ob, w2s, Zsum);
    obs_kern<<<B_DIM * T_DIM / 4, blk256, 0, stream>>>(Rterm, term_ow, term_ob, w2s,
                                                       text, Zsum, obs);
    pot_kern<<<B_DIM * (T_DIM - 1), blk64, 0, stream>>>(TL, obs, startv, text, w2s, P);
    scan_kern<<<B_DIM, blk64, 0, stream>>>(P, evid);
    out_kern<<<1, 64, 0, stream>>>(evid, (float*)d_out);
}

// Round 5
// 448.407 us; speedup vs baseline: 1.3749x; 1.2050x over previous
//
#include <hip/hip_runtime.h>
#include <hip/hip_bf16.h>

#define C_DIM 1024
#define H_DIM 512
#define V_DIM 32000
#define B_DIM 16
#define T_DIM 256
#define SPW   8
#define NSLOT 64

typedef unsigned short u16;
typedef unsigned int   u32;
typedef __attribute__((ext_vector_type(8))) short bf16x8;
typedef __attribute__((ext_vector_type(4))) float f32x4;

__device__ __forceinline__ u16 f2b(float f) {
    union { float f; u32 i; } x; x.f = f;
    u32 i = x.i;
    i += 0x7fffu + ((i >> 16) & 1u);   // RNE
    return (u16)(i >> 16);
}
__device__ __forceinline__ u32 pk2(float a, float b) {
    return (u32)f2b(a) | ((u32)f2b(b) << 16);
}

// ---------------- MFMA GEMM: out = act(A@B^T + bias) (+resid), f32 in/out -------
__global__ __launch_bounds__(256) void gemm_kern(
    const float* __restrict__ A, const float* __restrict__ B,
    const float* __restrict__ bias, const float* __restrict__ resid,
    float* __restrict__ out, int M, int N, int K, int flags)
{
    __shared__ __align__(16) u16 As[64][40];
    __shared__ __align__(16) u16 Bs[64][40];
    int tid  = threadIdx.x;
    int m0 = blockIdx.x * 64, n0 = blockIdx.y * 64;
    int wave = tid >> 6, lane = tid & 63;
    int wr = wave >> 1, wc = wave & 1;
    int srow = tid >> 2, scol = (tid & 3) << 3;
    int quad = lane >> 4, l16 = lane & 15;
    f32x4 acc[2][2] = {};

    for (int k0 = 0; k0 < K; k0 += 32) {
        const float4* ap = (const float4*)(A + (size_t)(m0 + srow) * K + k0 + scol);
        const float4* bp = (const float4*)(B + (size_t)(n0 + srow) * K + k0 + scol);
        float4 a0 = ap[0], a1 = ap[1];
        float4 b0 = bp[0], b1 = bp[1];
        __syncthreads();
        uint4 pa, pb;
        pa.x = pk2(a0.x, a0.y); pa.y = pk2(a0.z, a0.w);
        pa.z = pk2(a1.x, a1.y); pa.w = pk2(a1.z, a1.w);
        pb.x = pk2(b0.x, b0.y); pb.y = pk2(b0.z, b0.w);
        pb.z = pk2(b1.x, b1.y); pb.w = pk2(b1.z, b1.w);
        *(uint4*)&As[srow][scol] = pa;
        *(uint4*)&Bs[srow][scol] = pb;
        __syncthreads();
        bf16x8 af0 = *(const bf16x8*)&As[wr * 32 + l16][quad * 8];
        bf16x8 af1 = *(const bf16x8*)&As[wr * 32 + 16 + l16][quad * 8];
        bf16x8 bf0 = *(const bf16x8*)&Bs[wc * 32 + l16][quad * 8];
        bf16x8 bf1 = *(const bf16x8*)&Bs[wc * 32 + 16 + l16][quad * 8];
        acc[0][0] = __builtin_amdgcn_mfma_f32_16x16x32_bf16(af0, bf0, acc[0][0], 0, 0, 0);
        acc[0][1] = __builtin_amdgcn_mfma_f32_16x16x32_bf16(af0, bf1, acc[0][1], 0, 0, 0);
        acc[1][0] = __builtin_amdgcn_mfma_f32_16x16x32_bf16(af1, bf0, acc[1][0], 0, 0, 0);
        acc[1][1] = __builtin_amdgcn_mfma_f32_16x16x32_bf16(af1, bf1, acc[1][1], 0, 0, 0);
    }
#pragma unroll
    for (int sm = 0; sm < 2; sm++)
#pragma unroll
        for (int sn = 0; sn < 2; sn++) {
            int n = n0 + wc * 32 + sn * 16 + l16;
            float bv = bias ? bias[n] : 0.0f;
#pragma unroll
            for (int reg = 0; reg < 4; reg++) {
                int m = m0 + wr * 32 + sm * 16 + quad * 4 + reg;
                float v = acc[sm][sn][reg] + bv;
                if (flags & 1) v = fmaxf(v, 0.0f);
                if (resid) v += resid[(size_t)m * N + n];
                out[(size_t)m * N + n] = v;
            }
        }
}

// ---------------- start logits: one wave per state row --------------------------
__global__ __launch_bounds__(256) void startlog_kern(
    const float* __restrict__ Rstart, const float* __restrict__ sow,
    const float* __restrict__ sob, float* __restrict__ startv)
{
    int wid = threadIdx.x >> 6, lane = threadIdx.x & 63;
    int c = blockIdx.x * 4 + wid;
    const float4* rp = (const float4*)(Rstart + (size_t)c * H_DIM);
    const float4* wp = (const float4*)(sow);
    float4 r0 = rp[lane * 2], r1 = rp[lane * 2 + 1];
    float4 w0 = wp[lane * 2], w1 = wp[lane * 2 + 1];
    float d = r0.x * w0.x + r0.y * w0.y + r0.z * w0.z + r0.w * w0.w
            + r1.x * w1.x + r1.y * w1.y + r1.z * w1.z + r1.w * w1.w;
    for (int off = 1; off < 64; off <<= 1) d += __shfl_xor(d, off, 64);
    if (lane == 0) startv[c] = d + sob[0];
}

// ---------------- start softmax: single block over C ----------------------------
__global__ __launch_bounds__(1024) void startsm_kern(float* __restrict__ startv)
{
    int c = threadIdx.x;
    float d = startv[c];
    __shared__ float red[1024];
    red[c] = expf(d);
    __syncthreads();
    for (int st = 512; st > 0; st >>= 1) {
        if (c < st) red[c] += red[c + st];
        __syncthreads();
    }
    __shared__ float lz;
    if (c == 0) lz = logf(red[0]);
    __syncthreads();
    startv[c] = d - lz;
}

// ---------------- row log_softmax in place on TL (1024 x 1024 f32) --------------
__global__ __launch_bounds__(256) void rowsm_kern(float* __restrict__ TL)
{
    int row = blockIdx.x, tid = threadIdx.x;
    float4* p = (float4*)(TL + (size_t)row * C_DIM);
    float4 v = p[tid];
    float s = expf(v.x) + expf(v.y) + expf(v.z) + expf(v.w);
    __shared__ float red[256];
    red[tid] = s;
    __syncthreads();
    for (int st = 128; st > 0; st >>= 1) {
        if (tid < st) red[tid] += red[tid + st];
        __syncthreads();
    }
    __shared__ float lz;
    if (tid == 0) lz = logf(red[0]);
    __syncthreads();
    v.x -= lz; v.y -= lz; v.z -= lz; v.w -= lz;
    p[tid] = v;
}

// ---------------- zero accumulators ---------------------------------------------
__global__ __launch_bounds__(1024) void init_kern(float* __restrict__ Zpart,
                                                  float* __restrict__ evid)
{
    Zpart[blockIdx.x * 1024 + threadIdx.x] = 0.0f;
    if (blockIdx.x == 0 && threadIdx.x == 0) *evid = 0.0f;
}

// ---------------- emission denominator: slotted atomics -------------------------
__global__ __launch_bounds__(256) void zsum_kern(
    const float* __restrict__ Rterm, const float* __restrict__ tow,
    const float* __restrict__ tob, const int* __restrict__ w2s,
    float* __restrict__ Zpart)
{
    int wid = threadIdx.x >> 6, lane = threadIdx.x & 63;
    int v = blockIdx.x * 4 + wid;
    float* slot = Zpart + (blockIdx.x & (NSLOT - 1)) * C_DIM;
    const float4* twp = (const float4*)(tow + (size_t)v * H_DIM);
    float4 tw0 = twp[lane * 2], tw1 = twp[lane * 2 + 1];
    float ob = tob[v];
    int cs[SPW];
#pragma unroll
    for (int s = 0; s < SPW; s++) cs[s] = w2s[v * SPW + s];
    float d[SPW];
#pragma unroll
    for (int s = 0; s < SPW; s++) {
        const float4* rp = (const float4*)(Rterm + (size_t)cs[s] * H_DIM);
        float4 r0 = rp[lane * 2], r1 = rp[lane * 2 + 1];
        d[s] = tw0.x * r0.x + tw0.y * r0.y + tw0.z * r0.z + tw0.w * r0.w
             + tw1.x * r1.x + tw1.y * r1.y + tw1.z * r1.z + tw1.w * r1.w;
        d[s] += __shfl_xor(d[s], 1, 64);
        d[s] += __shfl_xor(d[s], 2, 64);
        d[s] += __shfl_xor(d[s], 4, 64);
    }
    float x = d[0];
    int myc = cs[0];
#pragma unroll
    for (int s = 1; s < SPW; s++) {
        if ((lane & 7) == s) { x = d[s]; myc = cs[s]; }
    }
    x += __shfl_xor(x, 8, 64);
    x += __shfl_xor(x, 16, 64);
    x += __shfl_xor(x, 32, 64);
    u32 dupmask = 0;
#pragma unroll
    for (int s = 1; s < SPW; s++) {
        bool dp = false;
#pragma unroll
        for (int s2 = 0; s2 < s; s2++) dp = dp || (cs[s2] == cs[s]);
        if (dp) dupmask |= (1u << s);
    }
    if (lane < 8 && !((dupmask >> lane) & 1u))
        atomicAdd(slot + myc, expf(x + ob));
}

// ---------------- reduce slots -> logZ ------------------------------------------
__global__ __launch_bounds__(256) void zred_kern(const float* __restrict__ Zpart,
                                                 float* __restrict__ logZ)
{
    int c = blockIdx.x * 256 + threadIdx.x;
    float s = 0.0f;
#pragma unroll
    for (int k = 0; k < NSLOT; k++) s += Zpart[k * C_DIM + c];
    logZ[c] = logf(s);
}

// ---------------- obs[b,t,s] = term_logit - logZ --------------------------------
__global__ __launch_bounds__(256) void obs_kern(
    const float* __restrict__ Rterm, const float* __restrict__ tow,
    const float* __restrict__ tob, const int* __restrict__ w2s,
    const int* __restrict__ text, const float* __restrict__ logZ,
    float* __restrict__ obs)
{
    int wid = threadIdx.x >> 6, lane = threadIdx.x & 63;
    int idx = blockIdx.x * 4 + wid;          // 0 .. B*T-1
    int v = text[idx];
    const float4* twp = (const float4*)(tow + (size_t)v * H_DIM);
    float4 tw0 = twp[lane * 2], tw1 = twp[lane * 2 + 1];
    float ob = tob[v];
    int cs[SPW];
#pragma unroll
    for (int s = 0; s < SPW; s++) cs[s] = w2s[v * SPW + s];
    float d[SPW];
#pragma unroll
    for (int s = 0; s < SPW; s++) {
        const float4* rp = (const float4*)(Rterm + (size_t)cs[s] * H_DIM);
        float4 r0 = rp[lane * 2], r1 = rp[lane * 2 + 1];
        d[s] = tw0.x * r0.x + tw0.y * r0.y + tw0.z * r0.z + tw0.w * r0.w
             + tw1.x * r1.x + tw1.y * r1.y + tw1.z * r1.z + tw1.w * r1.w;
        d[s] += __shfl_xor(d[s], 1, 64);
        d[s] += __shfl_xor(d[s], 2, 64);
        d[s] += __shfl_xor(d[s], 4, 64);
    }
    float x = d[0];
    int myc = cs[0];
#pragma unroll
    for (int s = 1; s < SPW; s++) {
        if ((lane & 7) == s) { x = d[s]; myc = cs[s]; }
    }
    x += __shfl_xor(x, 8, 64);
    x += __shfl_xor(x, 16, 64);
    x += __shfl_xor(x, 32, 64);
    if (lane < 8)
        obs[idx * SPW + lane] = x + ob - logZ[myc];
}

// ---------------- potential gather: P[b][t][j*8+i] ------------------------------
__global__ __launch_bounds__(64) void pot_kern(
    const float* __restrict__ trans, const float* __restrict__ obs,
    const float* __restrict__ start, const int* __restrict__ text,
    const int* __restrict__ w2s, float* __restrict__ P)
{
    int bt = blockIdx.x;
    int b = bt / (T_DIM - 1), t = bt % (T_DIM - 1);
    int lane = threadIdx.x;
    int j = lane >> 3, i = lane & 7;
    int vt  = text[b * T_DIM + t];
    int vt1 = text[b * T_DIM + t + 1];
    int ci = w2s[vt * SPW + i];
    int cj = w2s[vt1 * SPW + j];
    float p = trans[(size_t)ci * C_DIM + cj] + obs[(b * T_DIM + t + 1) * SPW + j];
    if (t == 0) p += start[ci] + obs[(b * T_DIM) * SPW + i];
    P[(size_t)bt * 64 + lane] = p;
}

// ---------------- forward scan: one wave per batch ------------------------------
__global__ __launch_bounds__(64) void scan_kern(const float* __restrict__ P,
                                                float* __restrict__ evid)
{
    int b = blockIdx.x, lane = threadIdx.x;
    const float* base = P + (size_t)b * (T_DIM - 1) * 64;
    float A = 0.0f, off = 0.0f;
    float pc = base[lane];
    for (int t = 0; t < T_DIM - 1; t++) {
        float pn = (t < T_DIM - 2) ? base[(size_t)(t + 1) * 64 + lane] : 0.0f;
        float av = __shfl(A, (lane & 7) << 3, 64);
        float x = pc + av;
        float m = x;
        m = fmaxf(m, __shfl_xor(m, 1, 64));
        m = fmaxf(m, __shfl_xor(m, 2, 64));
        m = fmaxf(m, __shfl_xor(m, 4, 64));
        float e = expf(x - m);
        e += __shfl_xor(e, 1, 64);
        e += __shfl_xor(e, 2, 64);
        e += __shfl_xor(e, 4, 64);
        float aj = m + logf(e);
        float g = aj;
        g = fmaxf(g, __shfl_xor(g, 8, 64));
        g = fmaxf(g, __shfl_xor(g, 16, 64));
        g = fmaxf(g, __shfl_xor(g, 32, 64));
        A = aj - g;
        off += g;
        pc = pn;
    }
    float ev = ((lane & 7) == 0) ? expf(A) : 0.0f;
    for (int o = 1; o < 64; o <<= 1) ev += __shfl_xor(ev, o, 64);
    if (lane == 0) atomicAdd(evid, off + logf(ev));
}

// ---------------- final scalar write (f32 out) ----------------------------------
__global__ void out_kern(const float* __restrict__ evid, float* __restrict__ out)
{
    if (threadIdx.x == 0) out[0] = *evid;
}

extern "C" void kernel_launch(void* const* d_in, const int* in_sizes, int n_in,
                              void* d_out, int out_size, void* d_ws, size_t ws_size,
                              hipStream_t stream)
{
    const float* start_emb = (const float*)d_in[0];
    const float* start_l1w = (const float*)d_in[1];
    const float* start_l1b = (const float*)d_in[2];
    const float* start_l2w = (const float*)d_in[3];
    const float* start_l2b = (const float*)d_in[4];
    const float* start_ow  = (const float*)d_in[5];
    const float* start_ob  = (const float*)d_in[6];
    const float* state_emb = (const float*)d_in[7];
    const float* trans_l1w = (const float*)d_in[8];
    const float* trans_l1b = (const float*)d_in[9];
    const float* trans_l2w = (const float*)d_in[10];
    const float* trans_l2b = (const float*)d_in[11];
    const float* proj_w    = (const float*)d_in[12];
    const float* pret_emb  = (const float*)d_in[13];
    const float* term_l1w  = (const float*)d_in[14];
    const float* term_l1b  = (const float*)d_in[15];
    const float* term_l2w  = (const float*)d_in[16];
    const float* term_l2b  = (const float*)d_in[17];
    const float* term_ow   = (const float*)d_in[18];
    const float* term_ob   = (const float*)d_in[19];
    const int*   text      = (const int*)d_in[20];
    const int*   w2s       = (const int*)d_in[21];

    char* w = (char*)d_ws;
    float* Hbuf   = (float*)(w);                            // 2 MB
    float* Rstart = (float*)(w + 2u * (1u << 20));          // 2 MB
    float* Rtrans = (float*)(w + 4u * (1u << 20));          // 2 MB
    float* Rterm  = (float*)(w + 6u * (1u << 20));          // 2 MB
    float* TL     = (float*)(w + 8u * (1u << 20));          // 4 MB
    float* startv = (float*)(w + 12u * (1u << 20));         // 4 KB
    float* logZ   = (float*)(w + 12u * (1u << 20) + 8192);  // 4 KB
    float* obs    = (float*)(w + 12u * (1u << 20) + 16384); // 128 KB
    float* P      = (float*)(w + 12u * (1u << 20) + 16384 + 131072);   // ~1 MB
    float* evid   = (float*)(w + 12u * (1u << 20) + 16384 + 131072 + 1048576);
    float* Zpart  = (float*)(w + 12u * (1u << 20) + 16384 + 131072 + 1048576 + 4096); // 256 KB

    dim3 blk256(256), blk64(64);

    init_kern<<<NSLOT, 1024, 0, stream>>>(Zpart, evid);

    gemm_kern<<<dim3(16, 8), blk256, 0, stream>>>(start_emb, start_l1w, start_l1b, nullptr,
                                                  Hbuf, C_DIM, H_DIM, H_DIM, 1);
    gemm_kern<<<dim3(16, 8), blk256, 0, stream>>>(Hbuf, start_l2w, start_l2b, start_emb,
                                                  Rstart, C_DIM, H_DIM, H_DIM, 1);
    gemm_kern<<<dim3(16, 8), blk256, 0, stream>>>(state_emb, trans_l1w, trans_l1b, nullptr,
                                                  Hbuf, C_DIM, H_DIM, H_DIM, 1);
    gemm_kern<<<dim3(16, 8), blk256, 0, stream>>>(Hbuf, trans_l2w, trans_l2b, state_emb,
                                                  Rtrans, C_DIM, H_DIM, H_DIM, 1);
    gemm_kern<<<dim3(16, 8), blk256, 0, stream>>>(pret_emb, term_l1w, term_l1b, nullptr,
                                                  Hbuf, C_DIM, H_DIM, H_DIM, 1);
    gemm_kern<<<dim3(16, 8), blk256, 0, stream>>>(Hbuf, term_l2w, term_l2b, pret_emb,
                                                  Rterm, C_DIM, H_DIM, H_DIM, 1);
    gemm_kern<<<dim3(16, 16), blk256, 0, stream>>>(Rtrans, proj_w, nullptr, nullptr,
                                                   TL, C_DIM, C_DIM, H_DIM, 0);

    startlog_kern<<<C_DIM / 4, blk256, 0, stream>>>(Rstart, start_ow, start_ob, startv);
    startsm_kern<<<1, 1024, 0, stream>>>(startv);
    rowsm_kern<<<C_DIM, blk256, 0, stream>>>(TL);

    zsum_kern<<<V_DIM / 4, blk256, 0, stream>>>(Rterm, term_ow, term_ob, w2s, Zpart);
    zred_kern<<<C_DIM / 256, blk256, 0, stream>>>(Zpart, logZ);
    obs_kern<<<B_DIM * T_DIM / 4, blk256, 0, stream>>>(Rterm, term_ow, term_ob, w2s,
                                                       text, logZ, obs);
    pot_kern<<<B_DIM * (T_DIM - 1), blk64, 0, stream>>>(TL, obs, startv, text, w2s, P);
    scan_kern<<<B_DIM, blk64, 0, stream>>>(P, evid);
    out_kern<<<1, 64, 0, stream>>>(evid, (float*)d_out);
}

// Round 6
// 296.929 us; speedup vs baseline: 2.0763x; 1.5101x over previous
//
#include <hip/hip_runtime.h>
#include <hip/hip_bf16.h>

#define C_DIM 1024
#define H_DIM 512
#define V_DIM 32000
#define B_DIM 16
#define T_DIM 256
#define SPW   8
#define NSLOT 64

typedef unsigned short u16;
typedef unsigned int   u32;
typedef __attribute__((ext_vector_type(8))) short bf16x8;
typedef __attribute__((ext_vector_type(4))) float f32x4;

__device__ __forceinline__ u16 f2b(float f) {
    union { float f; u32 i; } x; x.f = f;
    u32 i = x.i;
    i += 0x7fffu + ((i >> 16) & 1u);   // RNE
    return (u16)(i >> 16);
}
__device__ __forceinline__ u32 pk2(float a, float b) {
    return (u32)f2b(a) | ((u32)f2b(b) << 16);
}

struct MlpArgs {
    const float* A[3];
    const float* W[3];
    const float* bias[3];
    const float* resid[3];   // may be null
    float*       out[3];
};

// ---------------- batched MFMA GEMM (3 same-shape problems, z = problem) --------
// out = relu(A@W^T + bias) (+resid).  M=1024, N=512, K=512 fixed shape.
__global__ __launch_bounds__(256) void mlp_kern(MlpArgs args)
{
    const int M = C_DIM, N = H_DIM, K = H_DIM;
    int z = blockIdx.z;
    const float* A = args.A[z];
    const float* B = args.W[z];
    const float* bias = args.bias[z];
    const float* resid = args.resid[z];
    float* out = args.out[z];

    __shared__ __align__(16) u16 As[64][40];
    __shared__ __align__(16) u16 Bs[64][40];
    int tid  = threadIdx.x;
    int m0 = blockIdx.x * 64, n0 = blockIdx.y * 64;
    int wave = tid >> 6, lane = tid & 63;
    int wr = wave >> 1, wc = wave & 1;
    int srow = tid >> 2, scol = (tid & 3) << 3;
    int quad = lane >> 4, l16 = lane & 15;
    f32x4 acc[2][2] = {};

    for (int k0 = 0; k0 < K; k0 += 32) {
        const float4* ap = (const float4*)(A + (size_t)(m0 + srow) * K + k0 + scol);
        const float4* bp = (const float4*)(B + (size_t)(n0 + srow) * K + k0 + scol);
        float4 a0 = ap[0], a1 = ap[1];
        float4 b0 = bp[0], b1 = bp[1];
        __syncthreads();
        uint4 pa, pb;
        pa.x = pk2(a0.x, a0.y); pa.y = pk2(a0.z, a0.w);
        pa.z = pk2(a1.x, a1.y); pa.w = pk2(a1.z, a1.w);
        pb.x = pk2(b0.x, b0.y); pb.y = pk2(b0.z, b0.w);
        pb.z = pk2(b1.x, b1.y); pb.w = pk2(b1.z, b1.w);
        *(uint4*)&As[srow][scol] = pa;
        *(uint4*)&Bs[srow][scol] = pb;
        __syncthreads();
        bf16x8 af0 = *(const bf16x8*)&As[wr * 32 + l16][quad * 8];
        bf16x8 af1 = *(const bf16x8*)&As[wr * 32 + 16 + l16][quad * 8];
        bf16x8 bf0 = *(const bf16x8*)&Bs[wc * 32 + l16][quad * 8];
        bf16x8 bf1 = *(const bf16x8*)&Bs[wc * 32 + 16 + l16][quad * 8];
        acc[0][0] = __builtin_amdgcn_mfma_f32_16x16x32_bf16(af0, bf0, acc[0][0], 0, 0, 0);
        acc[0][1] = __builtin_amdgcn_mfma_f32_16x16x32_bf16(af0, bf1, acc[0][1], 0, 0, 0);
        acc[1][0] = __builtin_amdgcn_mfma_f32_16x16x32_bf16(af1, bf0, acc[1][0], 0, 0, 0);
        acc[1][1] = __builtin_amdgcn_mfma_f32_16x16x32_bf16(af1, bf1, acc[1][1], 0, 0, 0);
    }
#pragma unroll
    for (int sm = 0; sm < 2; sm++)
#pragma unroll
        for (int sn = 0; sn < 2; sn++) {
            int n = n0 + wc * 32 + sn * 16 + l16;
            float bv = bias[n];
#pragma unroll
            for (int reg = 0; reg < 4; reg++) {
                int m = m0 + wr * 32 + sm * 16 + quad * 4 + reg;
                float v = fmaxf(acc[sm][sn][reg] + bv, 0.0f);
                if (resid) v += resid[(size_t)m * N + n];
                out[(size_t)m * N + n] = v;
            }
        }
}

// ---------------- single MFMA GEMM (trans logits), no bias/act ------------------
__global__ __launch_bounds__(256) void gemm_kern(
    const float* __restrict__ A, const float* __restrict__ B,
    float* __restrict__ out, int M, int N, int K)
{
    __shared__ __align__(16) u16 As[64][40];
    __shared__ __align__(16) u16 Bs[64][40];
    int tid  = threadIdx.x;
    int m0 = blockIdx.x * 64, n0 = blockIdx.y * 64;
    int wave = tid >> 6, lane = tid & 63;
    int wr = wave >> 1, wc = wave & 1;
    int srow = tid >> 2, scol = (tid & 3) << 3;
    int quad = lane >> 4, l16 = lane & 15;
    f32x4 acc[2][2] = {};

    for (int k0 = 0; k0 < K; k0 += 32) {
        const float4* ap = (const float4*)(A + (size_t)(m0 + srow) * K + k0 + scol);
        const float4* bp = (const float4*)(B + (size_t)(n0 + srow) * K + k0 + scol);
        float4 a0 = ap[0], a1 = ap[1];
        float4 b0 = bp[0], b1 = bp[1];
        __syncthreads();
        uint4 pa, pb;
        pa.x = pk2(a0.x, a0.y); pa.y = pk2(a0.z, a0.w);
        pa.z = pk2(a1.x, a1.y); pa.w = pk2(a1.z, a1.w);
        pb.x = pk2(b0.x, b0.y); pb.y = pk2(b0.z, b0.w);
        pb.z = pk2(b1.x, b1.y); pb.w = pk2(b1.z, b1.w);
        *(uint4*)&As[srow][scol] = pa;
        *(uint4*)&Bs[srow][scol] = pb;
        __syncthreads();
        bf16x8 af0 = *(const bf16x8*)&As[wr * 32 + l16][quad * 8];
        bf16x8 af1 = *(const bf16x8*)&As[wr * 32 + 16 + l16][quad * 8];
        bf16x8 bf0 = *(const bf16x8*)&Bs[wc * 32 + l16][quad * 8];
        bf16x8 bf1 = *(const bf16x8*)&Bs[wc * 32 + 16 + l16][quad * 8];
        acc[0][0] = __builtin_amdgcn_mfma_f32_16x16x32_bf16(af0, bf0, acc[0][0], 0, 0, 0);
        acc[0][1] = __builtin_amdgcn_mfma_f32_16x16x32_bf16(af0, bf1, acc[0][1], 0, 0, 0);
        acc[1][0] = __builtin_amdgcn_mfma_f32_16x16x32_bf16(af1, bf0, acc[1][0], 0, 0, 0);
        acc[1][1] = __builtin_amdgcn_mfma_f32_16x16x32_bf16(af1, bf1, acc[1][1], 0, 0, 0);
    }
#pragma unroll
    for (int sm = 0; sm < 2; sm++)
#pragma unroll
        for (int sn = 0; sn < 2; sn++) {
            int n = n0 + wc * 32 + sn * 16 + l16;
#pragma unroll
            for (int reg = 0; reg < 4; reg++) {
                int m = m0 + wr * 32 + sm * 16 + quad * 4 + reg;
                out[(size_t)m * N + n] = acc[sm][sn][reg];
            }
        }
}

// ---------------- start logits: one wave per state row --------------------------
__global__ __launch_bounds__(256) void startlog_kern(
    const float* __restrict__ Rstart, const float* __restrict__ sow,
    const float* __restrict__ sob, float* __restrict__ startv)
{
    int wid = threadIdx.x >> 6, lane = threadIdx.x & 63;
    int c = blockIdx.x * 4 + wid;
    const float4* rp = (const float4*)(Rstart + (size_t)c * H_DIM);
    const float4* wp = (const float4*)(sow);
    float4 r0 = rp[lane * 2], r1 = rp[lane * 2 + 1];
    float4 w0 = wp[lane * 2], w1 = wp[lane * 2 + 1];
    float d = r0.x * w0.x + r0.y * w0.y + r0.z * w0.z + r0.w * w0.w
            + r1.x * w1.x + r1.y * w1.y + r1.z * w1.z + r1.w * w1.w;
    for (int off = 1; off < 64; off <<= 1) d += __shfl_xor(d, off, 64);
    if (lane == 0) startv[c] = d + sob[0];
}

// ---------------- start softmax: single block over C ----------------------------
__global__ __launch_bounds__(1024) void startsm_kern(float* __restrict__ startv)
{
    int c = threadIdx.x;
    float d = startv[c];
    __shared__ float red[1024];
    red[c] = expf(d);
    __syncthreads();
    for (int st = 512; st > 0; st >>= 1) {
        if (c < st) red[c] += red[c + st];
        __syncthreads();
    }
    __shared__ float lz;
    if (c == 0) lz = logf(red[0]);
    __syncthreads();
    startv[c] = d - lz;
}

// ---------------- row log_softmax in place on TL (1024 x 1024 f32) --------------
__global__ __launch_bounds__(256) void rowsm_kern(float* __restrict__ TL)
{
    int row = blockIdx.x, tid = threadIdx.x;
    float4* p = (float4*)(TL + (size_t)row * C_DIM);
    float4 v = p[tid];
    float s = expf(v.x) + expf(v.y) + expf(v.z) + expf(v.w);
    __shared__ float red[256];
    red[tid] = s;
    __syncthreads();
    for (int st = 128; st > 0; st >>= 1) {
        if (tid < st) red[tid] += red[tid + st];
        __syncthreads();
    }
    __shared__ float lz;
    if (tid == 0) lz = logf(red[0]);
    __syncthreads();
    v.x -= lz; v.y -= lz; v.z -= lz; v.w -= lz;
    p[tid] = v;
}

// ---------------- zero accumulators ---------------------------------------------
__global__ __launch_bounds__(1024) void init_kern(float* __restrict__ Zpart,
                                                  float* __restrict__ evid)
{
    Zpart[blockIdx.x * 1024 + threadIdx.x] = 0.0f;
    if (blockIdx.x == 0 && threadIdx.x == 0) *evid = 0.0f;
}

// ---------------- emission denominator: slotted atomics -------------------------
__global__ __launch_bounds__(256) void zsum_kern(
    const float* __restrict__ Rterm, const float* __restrict__ tow,
    const float* __restrict__ tob, const int* __restrict__ w2s,
    float* __restrict__ Zpart)
{
    int wid = threadIdx.x >> 6, lane = threadIdx.x & 63;
    int v = blockIdx.x * 4 + wid;
    float* slot = Zpart + (blockIdx.x & (NSLOT - 1)) * C_DIM;
    const float4* twp = (const float4*)(tow + (size_t)v * H_DIM);
    float4 tw0 = twp[lane * 2], tw1 = twp[lane * 2 + 1];
    float ob = tob[v];
    int cs[SPW];
#pragma unroll
    for (int s = 0; s < SPW; s++) cs[s] = w2s[v * SPW + s];
    float d[SPW];
#pragma unroll
    for (int s = 0; s < SPW; s++) {
        const float4* rp = (const float4*)(Rterm + (size_t)cs[s] * H_DIM);
        float4 r0 = rp[lane * 2], r1 = rp[lane * 2 + 1];
        d[s] = tw0.x * r0.x + tw0.y * r0.y + tw0.z * r0.z + tw0.w * r0.w
             + tw1.x * r1.x + tw1.y * r1.y + tw1.z * r1.z + tw1.w * r1.w;
        d[s] += __shfl_xor(d[s], 1, 64);
        d[s] += __shfl_xor(d[s], 2, 64);
        d[s] += __shfl_xor(d[s], 4, 64);
    }
    float x = d[0];
    int myc = cs[0];
#pragma unroll
    for (int s = 1; s < SPW; s++) {
        if ((lane & 7) == s) { x = d[s]; myc = cs[s]; }
    }
    x += __shfl_xor(x, 8, 64);
    x += __shfl_xor(x, 16, 64);
    x += __shfl_xor(x, 32, 64);
    u32 dupmask = 0;
#pragma unroll
    for (int s = 1; s < SPW; s++) {
        bool dp = false;
#pragma unroll
        for (int s2 = 0; s2 < s; s2++) dp = dp || (cs[s2] == cs[s]);
        if (dp) dupmask |= (1u << s);
    }
    if (lane < 8 && !((dupmask >> lane) & 1u))
        atomicAdd(slot + myc, expf(x + ob));
}

// ---------------- reduce slots -> logZ ------------------------------------------
__global__ __launch_bounds__(256) void zred_kern(const float* __restrict__ Zpart,
                                                 float* __restrict__ logZ)
{
    int c = blockIdx.x * 256 + threadIdx.x;
    float s = 0.0f;
#pragma unroll
    for (int k = 0; k < NSLOT; k++) s += Zpart[k * C_DIM + c];
    logZ[c] = logf(s);
}

// ---------------- obs[b,t,s] = term_logit - logZ --------------------------------
__global__ __launch_bounds__(256) void obs_kern(
    const float* __restrict__ Rterm, const float* __restrict__ tow,
    const float* __restrict__ tob, const int* __restrict__ w2s,
    const int* __restrict__ text, const float* __restrict__ logZ,
    float* __restrict__ obs)
{
    int wid = threadIdx.x >> 6, lane = threadIdx.x & 63;
    int idx = blockIdx.x * 4 + wid;          // 0 .. B*T-1
    int v = text[idx];
    const float4* twp = (const float4*)(tow + (size_t)v * H_DIM);
    float4 tw0 = twp[lane * 2], tw1 = twp[lane * 2 + 1];
    float ob = tob[v];
    int cs[SPW];
#pragma unroll
    for (int s = 0; s < SPW; s++) cs[s] = w2s[v * SPW + s];
    float d[SPW];
#pragma unroll
    for (int s = 0; s < SPW; s++) {
        const float4* rp = (const float4*)(Rterm + (size_t)cs[s] * H_DIM);
        float4 r0 = rp[lane * 2], r1 = rp[lane * 2 + 1];
        d[s] = tw0.x * r0.x + tw0.y * r0.y + tw0.z * r0.z + tw0.w * r0.w
             + tw1.x * r1.x + tw1.y * r1.y + tw1.z * r1.z + tw1.w * r1.w;
        d[s] += __shfl_xor(d[s], 1, 64);
        d[s] += __shfl_xor(d[s], 2, 64);
        d[s] += __shfl_xor(d[s], 4, 64);
    }
    float x = d[0];
    int myc = cs[0];
#pragma unroll
    for (int s = 1; s < SPW; s++) {
        if ((lane & 7) == s) { x = d[s]; myc = cs[s]; }
    }
    x += __shfl_xor(x, 8, 64);
    x += __shfl_xor(x, 16, 64);
    x += __shfl_xor(x, 32, 64);
    if (lane < 8)
        obs[idx * SPW + lane] = x + ob - logZ[myc];
}

// ---------------- potential gather: P[b][t][j*8+i] ------------------------------
__global__ __launch_bounds__(64) void pot_kern(
    const float* __restrict__ trans, const float* __restrict__ obs,
    const float* __restrict__ start, const int* __restrict__ text,
    const int* __restrict__ w2s, float* __restrict__ P)
{
    int bt = blockIdx.x;
    int b = bt / (T_DIM - 1), t = bt % (T_DIM - 1);
    int lane = threadIdx.x;
    int j = lane >> 3, i = lane & 7;
    int vt  = text[b * T_DIM + t];
    int vt1 = text[b * T_DIM + t + 1];
    int ci = w2s[vt * SPW + i];
    int cj = w2s[vt1 * SPW + j];
    float p = trans[(size_t)ci * C_DIM + cj] + obs[(b * T_DIM + t + 1) * SPW + j];
    if (t == 0) p += start[ci] + obs[(b * T_DIM) * SPW + i];
    P[(size_t)bt * 64 + lane] = p;
}

// ---------------- log-semiring 8x8 matrix combine (lane = j*8+i) ----------------
__device__ __forceinline__ float lsm_combine(float accv, float mv, int i, int j)
{
    float x[8];
#pragma unroll
    for (int k = 0; k < 8; k++) {
        float a = __shfl(accv, k * 8 + i, 64);   // acc[i][k]
        float b = __shfl(mv,  j * 8 + k, 64);    // m[k][j]
        x[k] = a + b;
    }
    float mx = fmaxf(fmaxf(fmaxf(x[0], x[1]), fmaxf(x[2], x[3])),
                     fmaxf(fmaxf(x[4], x[5]), fmaxf(x[6], x[7])));
    float s = 0.0f;
#pragma unroll
    for (int k = 0; k < 8; k++) s += expf(x[k] - mx);
    return mx + logf(s);
}

// ---------------- scan phase A: each wave folds 16 consecutive M matrices -------
__global__ __launch_bounds__(256) void scanA_kern(const float* __restrict__ P,
                                                  float* __restrict__ Mc)
{
    int wid = threadIdx.x >> 6, lane = threadIdx.x & 63;
    int g = blockIdx.x * 4 + wid;        // 0 .. 255
    int b = g >> 4, c = g & 15;
    int t0 = c * 16;
    int cnt = min(16, (T_DIM - 1) - t0);
    const float* base = P + ((size_t)b * (T_DIM - 1) + t0) * 64;
    int i = lane & 7, j = lane >> 3;
    float acc = base[lane];
    for (int t = 1; t < cnt; t++)
        acc = lsm_combine(acc, base[(size_t)t * 64 + lane], i, j);
    Mc[(size_t)g * 64 + lane] = acc;
}

// ---------------- scan phase B: fold 16 chunk matrices, reduce to evidence ------
__global__ __launch_bounds__(64) void scanB_kern(const float* __restrict__ Mc,
                                                 float* __restrict__ evid)
{
    int b = blockIdx.x, lane = threadIdx.x;
    int i = lane & 7, j = lane >> 3;
    const float* base = Mc + (size_t)b * 16 * 64;
    float acc = base[lane];
    for (int c = 1; c < 16; c++)
        acc = lsm_combine(acc, base[(size_t)c * 64 + lane], i, j);
    float mx = acc;
    for (int o = 1; o < 64; o <<= 1) mx = fmaxf(mx, __shfl_xor(mx, o, 64));
    float e = expf(acc - mx);
    for (int o = 1; o < 64; o <<= 1) e += __shfl_xor(e, o, 64);
    if (lane == 0) atomicAdd(evid, mx + logf(e));
}

// ---------------- final scalar write (f32 out) ----------------------------------
__global__ void out_kern(const float* __restrict__ evid, float* __restrict__ out)
{
    if (threadIdx.x == 0) out[0] = *evid;
}

extern "C" void kernel_launch(void* const* d_in, const int* in_sizes, int n_in,
                              void* d_out, int out_size, void* d_ws, size_t ws_size,
                              hipStream_t stream)
{
    const float* start_emb = (const float*)d_in[0];
    const float* start_l1w = (const float*)d_in[1];
    const float* start_l1b = (const float*)d_in[2];
    const float* start_l2w = (const float*)d_in[3];
    const float* start_l2b = (const float*)d_in[4];
    const float* start_ow  = (const float*)d_in[5];
    const float* start_ob  = (const float*)d_in[6];
    const float* state_emb = (const float*)d_in[7];
    const float* trans_l1w = (const float*)d_in[8];
    const float* trans_l1b = (const float*)d_in[9];
    const float* trans_l2w = (const float*)d_in[10];
    const float* trans_l2b = (const float*)d_in[11];
    const float* proj_w    = (const float*)d_in[12];
    const float* pret_emb  = (const float*)d_in[13];
    const float* term_l1w  = (const float*)d_in[14];
    const float* term_l1b  = (const float*)d_in[15];
    const float* term_l2w  = (const float*)d_in[16];
    const float* term_l2b  = (const float*)d_in[17];
    const float* term_ow   = (const float*)d_in[18];
    const float* term_ob   = (const float*)d_in[19];
    const int*   text      = (const int*)d_in[20];
    const int*   w2s       = (const int*)d_in[21];

    char* w = (char*)d_ws;
    const u32 MB = 1u << 20;
    float* H3     = (float*)(w);                 // 6 MB (3x 1024x512)
    float* R3     = (float*)(w + 6u * MB);       // 6 MB (Rstart,Rtrans,Rterm)
    float* TL     = (float*)(w + 12u * MB);      // 4 MB
    float* startv = (float*)(w + 16u * MB);              // 4 KB
    float* logZ   = (float*)(w + 16u * MB + 8192);       // 4 KB
    float* obs    = (float*)(w + 16u * MB + 16384);      // 128 KB
    float* P      = (float*)(w + 16u * MB + 16384 + 131072);              // ~1 MB
    float* evid   = (float*)(w + 16u * MB + 16384 + 131072 + 1048576);
    float* Zpart  = (float*)(w + 16u * MB + 16384 + 131072 + 1048576 + 4096);   // 256 KB
    float* Mc     = (float*)(w + 16u * MB + 16384 + 131072 + 1048576 + 4096 + 262144); // 64 KB

    float* Hs = H3;
    float* Ht = H3 + (size_t)C_DIM * H_DIM;
    float* Hp = H3 + 2 * (size_t)C_DIM * H_DIM;
    float* Rstart = R3;
    float* Rtrans = R3 + (size_t)C_DIM * H_DIM;
    float* Rterm  = R3 + 2 * (size_t)C_DIM * H_DIM;

    dim3 blk256(256), blk64(64);

    init_kern<<<NSLOT, 1024, 0, stream>>>(Zpart, evid);

    MlpArgs l1 = {{start_emb, state_emb, pret_emb},
                  {start_l1w, trans_l1w, term_l1w},
                  {start_l1b, trans_l1b, term_l1b},
                  {nullptr, nullptr, nullptr},
                  {Hs, Ht, Hp}};
    MlpArgs l2 = {{Hs, Ht, Hp},
                  {start_l2w, trans_l2w, term_l2w},
                  {start_l2b, trans_l2b, term_l2b},
                  {start_emb, state_emb, pret_emb},
                  {Rstart, Rtrans, Rterm}};
    mlp_kern<<<dim3(16, 8, 3), blk256, 0, stream>>>(l1);
    mlp_kern<<<dim3(16, 8, 3), blk256, 0, stream>>>(l2);

    gemm_kern<<<dim3(16, 16), blk256, 0, stream>>>(Rtrans, proj_w, TL,
                                                   C_DIM, C_DIM, H_DIM);

    startlog_kern<<<C_DIM / 4, blk256, 0, stream>>>(Rstart, start_ow, start_ob, startv);
    startsm_kern<<<1, 1024, 0, stream>>>(startv);
    rowsm_kern<<<C_DIM, blk256, 0, stream>>>(TL);

    zsum_kern<<<V_DIM / 4, blk256, 0, stream>>>(Rterm, term_ow, term_ob, w2s, Zpart);
    zred_kern<<<C_DIM / 256, blk256, 0, stream>>>(Zpart, logZ);
    obs_kern<<<B_DIM * T_DIM / 4, blk256, 0, stream>>>(Rterm, term_ow, term_ob, w2s,
                                                       text, logZ, obs);
    pot_kern<<<B_DIM * (T_DIM - 1), blk64, 0, stream>>>(TL, obs, startv, text, w2s, P);

    scanA_kern<<<B_DIM * 16 / 4, blk256, 0, stream>>>(P, Mc);
    scanB_kern<<<B_DIM, blk64, 0, stream>>>(Mc, evid);
    out_kern<<<1, 64, 0, stream>>>(evid, (float*)d_out);
}

// Round 7
// 282.047 us; speedup vs baseline: 2.1858x; 1.0528x over previous
//
#include <hip/hip_runtime.h>
#include <hip/hip_bf16.h>

#define C_DIM 1024
#define H_DIM 512
#define V_DIM 32000
#define B_DIM 16
#define T_DIM 256
#define SPW   8
#define NSLOT 64

typedef unsigned short u16;
typedef unsigned int   u32;
typedef __attribute__((ext_vector_type(8))) short bf16x8;
typedef __attribute__((ext_vector_type(4))) float f32x4;

__device__ __forceinline__ u16 f2b(float f) {
    union { float f; u32 i; } x; x.f = f;
    u32 i = x.i;
    i += 0x7fffu + ((i >> 16) & 1u);   // RNE
    return (u16)(i >> 16);
}
__device__ __forceinline__ u32 pk2(float a, float b) {
    return (u32)f2b(a) | ((u32)f2b(b) << 16);
}
__device__ __forceinline__ float b2f(u16 u) {
    union { u32 i; float f; } x; x.i = ((u32)u) << 16; return x.f;
}
__device__ __forceinline__ float dot8_bf16(uint4 u, const float4 tw0, const float4 tw1) {
    return tw0.x * b2f((u16)(u.x & 0xffff)) + tw0.y * b2f((u16)(u.x >> 16))
         + tw0.z * b2f((u16)(u.y & 0xffff)) + tw0.w * b2f((u16)(u.y >> 16))
         + tw1.x * b2f((u16)(u.z & 0xffff)) + tw1.y * b2f((u16)(u.z >> 16))
         + tw1.z * b2f((u16)(u.w & 0xffff)) + tw1.w * b2f((u16)(u.w >> 16));
}

struct MlpArgs {
    const float* A[3];
    const float* W[3];
    const float* bias[3];
    const float* resid[3];   // may be null
    float*       out[3];     // may be null
    u16*         out16[3];   // may be null (bf16 secondary output)
};

// ---------------- batched MFMA GEMM (3 same-shape problems, z = problem) --------
// out = relu(A@W^T + bias) (+resid).  M=1024, N=512, K=512 fixed shape.
__global__ __launch_bounds__(256) void mlp_kern(MlpArgs args)
{
    const int N = H_DIM, K = H_DIM;
    int z = blockIdx.z;
    const float* A = args.A[z];
    const float* B = args.W[z];
    const float* bias = args.bias[z];
    const float* resid = args.resid[z];
    float* out = args.out[z];
    u16* out16 = args.out16[z];

    __shared__ __align__(16) u16 As[64][40];
    __shared__ __align__(16) u16 Bs[64][40];
    int tid  = threadIdx.x;
    int m0 = blockIdx.x * 64, n0 = blockIdx.y * 64;
    int wave = tid >> 6, lane = tid & 63;
    int wr = wave >> 1, wc = wave & 1;
    int srow = tid >> 2, scol = (tid & 3) << 3;
    int quad = lane >> 4, l16 = lane & 15;
    f32x4 acc[2][2] = {};

    for (int k0 = 0; k0 < K; k0 += 32) {
        const float4* ap = (const float4*)(A + (size_t)(m0 + srow) * K + k0 + scol);
        const float4* bp = (const float4*)(B + (size_t)(n0 + srow) * K + k0 + scol);
        float4 a0 = ap[0], a1 = ap[1];
        float4 b0 = bp[0], b1 = bp[1];
        __syncthreads();
        uint4 pa, pb;
        pa.x = pk2(a0.x, a0.y); pa.y = pk2(a0.z, a0.w);
        pa.z = pk2(a1.x, a1.y); pa.w = pk2(a1.z, a1.w);
        pb.x = pk2(b0.x, b0.y); pb.y = pk2(b0.z, b0.w);
        pb.z = pk2(b1.x, b1.y); pb.w = pk2(b1.z, b1.w);
        *(uint4*)&As[srow][scol] = pa;
        *(uint4*)&Bs[srow][scol] = pb;
        __syncthreads();
        bf16x8 af0 = *(const bf16x8*)&As[wr * 32 + l16][quad * 8];
        bf16x8 af1 = *(const bf16x8*)&As[wr * 32 + 16 + l16][quad * 8];
        bf16x8 bf0 = *(const bf16x8*)&Bs[wc * 32 + l16][quad * 8];
        bf16x8 bf1 = *(const bf16x8*)&Bs[wc * 32 + 16 + l16][quad * 8];
        acc[0][0] = __builtin_amdgcn_mfma_f32_16x16x32_bf16(af0, bf0, acc[0][0], 0, 0, 0);
        acc[0][1] = __builtin_amdgcn_mfma_f32_16x16x32_bf16(af0, bf1, acc[0][1], 0, 0, 0);
        acc[1][0] = __builtin_amdgcn_mfma_f32_16x16x32_bf16(af1, bf0, acc[1][0], 0, 0, 0);
        acc[1][1] = __builtin_amdgcn_mfma_f32_16x16x32_bf16(af1, bf1, acc[1][1], 0, 0, 0);
    }
#pragma unroll
    for (int sm = 0; sm < 2; sm++)
#pragma unroll
        for (int sn = 0; sn < 2; sn++) {
            int n = n0 + wc * 32 + sn * 16 + l16;
            float bv = bias[n];
#pragma unroll
            for (int reg = 0; reg < 4; reg++) {
                int m = m0 + wr * 32 + sm * 16 + quad * 4 + reg;
                float v = fmaxf(acc[sm][sn][reg] + bv, 0.0f);
                if (resid) v += resid[(size_t)m * N + n];
                if (out)   out[(size_t)m * N + n] = v;
                if (out16) out16[(size_t)m * N + n] = f2b(v);
            }
        }
}

// ---------------- single MFMA GEMM (trans logits), no bias/act ------------------
__global__ __launch_bounds__(256) void gemm_kern(
    const float* __restrict__ A, const float* __restrict__ B,
    float* __restrict__ out, int M, int N, int K)
{
    __shared__ __align__(16) u16 As[64][40];
    __shared__ __align__(16) u16 Bs[64][40];
    int tid  = threadIdx.x;
    int m0 = blockIdx.x * 64, n0 = blockIdx.y * 64;
    int wave = tid >> 6, lane = tid & 63;
    int wr = wave >> 1, wc = wave & 1;
    int srow = tid >> 2, scol = (tid & 3) << 3;
    int quad = lane >> 4, l16 = lane & 15;
    f32x4 acc[2][2] = {};

    for (int k0 = 0; k0 < K; k0 += 32) {
        const float4* ap = (const float4*)(A + (size_t)(m0 + srow) * K + k0 + scol);
        const float4* bp = (const float4*)(B + (size_t)(n0 + srow) * K + k0 + scol);
        float4 a0 = ap[0], a1 = ap[1];
        float4 b0 = bp[0], b1 = bp[1];
        __syncthreads();
        uint4 pa, pb;
        pa.x = pk2(a0.x, a0.y); pa.y = pk2(a0.z, a0.w);
        pa.z = pk2(a1.x, a1.y); pa.w = pk2(a1.z, a1.w);
        pb.x = pk2(b0.x, b0.y); pb.y = pk2(b0.z, b0.w);
        pb.z = pk2(b1.x, b1.y); pb.w = pk2(b1.z, b1.w);
        *(uint4*)&As[srow][scol] = pa;
        *(uint4*)&Bs[srow][scol] = pb;
        __syncthreads();
        bf16x8 af0 = *(const bf16x8*)&As[wr * 32 + l16][quad * 8];
        bf16x8 af1 = *(const bf16x8*)&As[wr * 32 + 16 + l16][quad * 8];
        bf16x8 bf0 = *(const bf16x8*)&Bs[wc * 32 + l16][quad * 8];
        bf16x8 bf1 = *(const bf16x8*)&Bs[wc * 32 + 16 + l16][quad * 8];
        acc[0][0] = __builtin_amdgcn_mfma_f32_16x16x32_bf16(af0, bf0, acc[0][0], 0, 0, 0);
        acc[0][1] = __builtin_amdgcn_mfma_f32_16x16x32_bf16(af0, bf1, acc[0][1], 0, 0, 0);
        acc[1][0] = __builtin_amdgcn_mfma_f32_16x16x32_bf16(af1, bf0, acc[1][0], 0, 0, 0);
        acc[1][1] = __builtin_amdgcn_mfma_f32_16x16x32_bf16(af1, bf1, acc[1][1], 0, 0, 0);
    }
#pragma unroll
    for (int sm = 0; sm < 2; sm++)
#pragma unroll
        for (int sn = 0; sn < 2; sn++) {
            int n = n0 + wc * 32 + sn * 16 + l16;
#pragma unroll
            for (int reg = 0; reg < 4; reg++) {
                int m = m0 + wr * 32 + sm * 16 + quad * 4 + reg;
                out[(size_t)m * N + n] = acc[sm][sn][reg];
            }
        }
}

// ---------------- start logits: one wave per state row --------------------------
__global__ __launch_bounds__(256) void startlog_kern(
    const float* __restrict__ Rstart, const float* __restrict__ sow,
    const float* __restrict__ sob, float* __restrict__ startv)
{
    int wid = threadIdx.x >> 6, lane = threadIdx.x & 63;
    int c = blockIdx.x * 4 + wid;
    const float4* rp = (const float4*)(Rstart + (size_t)c * H_DIM);
    const float4* wp = (const float4*)(sow);
    float4 r0 = rp[lane * 2], r1 = rp[lane * 2 + 1];
    float4 w0 = wp[lane * 2], w1 = wp[lane * 2 + 1];
    float d = r0.x * w0.x + r0.y * w0.y + r0.z * w0.z + r0.w * w0.w
            + r1.x * w1.x + r1.y * w1.y + r1.z * w1.z + r1.w * w1.w;
    for (int off = 1; off < 64; off <<= 1) d += __shfl_xor(d, off, 64);
    if (lane == 0) startv[c] = d + sob[0];
}

// ---------------- start softmax: single block over C ----------------------------
__global__ __launch_bounds__(1024) void startsm_kern(float* __restrict__ startv)
{
    int c = threadIdx.x;
    float d = startv[c];
    __shared__ float red[1024];
    red[c] = expf(d);
    __syncthreads();
    for (int st = 512; st > 0; st >>= 1) {
        if (c < st) red[c] += red[c + st];
        __syncthreads();
    }
    __shared__ float lz;
    if (c == 0) lz = logf(red[0]);
    __syncthreads();
    startv[c] = d - lz;
}

// ---------------- row log_softmax in place on TL (1024 x 1024 f32) --------------
__global__ __launch_bounds__(256) void rowsm_kern(float* __restrict__ TL)
{
    int row = blockIdx.x, tid = threadIdx.x;
    float4* p = (float4*)(TL + (size_t)row * C_DIM);
    float4 v = p[tid];
    float s = expf(v.x) + expf(v.y) + expf(v.z) + expf(v.w);
    __shared__ float red[256];
    red[tid] = s;
    __syncthreads();
    for (int st = 128; st > 0; st >>= 1) {
        if (tid < st) red[tid] += red[tid + st];
        __syncthreads();
    }
    __shared__ float lz;
    if (tid == 0) lz = logf(red[0]);
    __syncthreads();
    v.x -= lz; v.y -= lz; v.z -= lz; v.w -= lz;
    p[tid] = v;
}

// ---------------- zero accumulators ---------------------------------------------
__global__ __launch_bounds__(1024) void init_kern(float* __restrict__ Zpart,
                                                  float* __restrict__ evid)
{
    Zpart[blockIdx.x * 1024 + threadIdx.x] = 0.0f;
    if (blockIdx.x == 0 && threadIdx.x == 0) *evid = 0.0f;
}

// ---------------- emission denominator: bf16 Rterm gather, slotted atomics ------
__global__ __launch_bounds__(256) void zsum_kern(
    const u16* __restrict__ Rterm16, const float* __restrict__ tow,
    const float* __restrict__ tob, const int* __restrict__ w2s,
    float* __restrict__ Zpart)
{
    int wid = threadIdx.x >> 6, lane = threadIdx.x & 63;
    int v = blockIdx.x * 4 + wid;
    float* slot = Zpart + (blockIdx.x & (NSLOT - 1)) * C_DIM;
    const float4* twp = (const float4*)(tow + (size_t)v * H_DIM);
    float4 tw0 = twp[lane * 2], tw1 = twp[lane * 2 + 1];
    float ob = tob[v];
    int cs[SPW];
#pragma unroll
    for (int s = 0; s < SPW; s++) cs[s] = w2s[v * SPW + s];
    uint4 rv[SPW];
#pragma unroll
    for (int s = 0; s < SPW; s++)
        rv[s] = ((const uint4*)(Rterm16 + (size_t)cs[s] * H_DIM))[lane];
    float d[SPW];
#pragma unroll
    for (int s = 0; s < SPW; s++) {
        d[s] = dot8_bf16(rv[s], tw0, tw1);
        d[s] += __shfl_xor(d[s], 1, 64);
        d[s] += __shfl_xor(d[s], 2, 64);
        d[s] += __shfl_xor(d[s], 4, 64);
    }
    float x = d[0];
    int myc = cs[0];
#pragma unroll
    for (int s = 1; s < SPW; s++) {
        if ((lane & 7) == s) { x = d[s]; myc = cs[s]; }
    }
    x += __shfl_xor(x, 8, 64);
    x += __shfl_xor(x, 16, 64);
    x += __shfl_xor(x, 32, 64);
    u32 dupmask = 0;
#pragma unroll
    for (int s = 1; s < SPW; s++) {
        bool dp = false;
#pragma unroll
        for (int s2 = 0; s2 < s; s2++) dp = dp || (cs[s2] == cs[s]);
        if (dp) dupmask |= (1u << s);
    }
    if (lane < 8 && !((dupmask >> lane) & 1u))
        atomicAdd(slot + myc, expf(x + ob));
}

// ---------------- reduce slots -> logZ ------------------------------------------
__global__ __launch_bounds__(256) void zred_kern(const float* __restrict__ Zpart,
                                                 float* __restrict__ logZ)
{
    int c = blockIdx.x * 256 + threadIdx.x;
    float s = 0.0f;
#pragma unroll
    for (int k = 0; k < NSLOT; k++) s += Zpart[k * C_DIM + c];
    logZ[c] = logf(s);
}

// ---------------- obs[b,t,s] = term_logit - logZ (bf16 Rterm) -------------------
__global__ __launch_bounds__(256) void obs_kern(
    const u16* __restrict__ Rterm16, const float* __restrict__ tow,
    const float* __restrict__ tob, const int* __restrict__ w2s,
    const int* __restrict__ text, const float* __restrict__ logZ,
    float* __restrict__ obs)
{
    int wid = threadIdx.x >> 6, lane = threadIdx.x & 63;
    int idx = blockIdx.x * 4 + wid;          // 0 .. B*T-1
    int v = text[idx];
    const float4* twp = (const float4*)(tow + (size_t)v * H_DIM);
    float4 tw0 = twp[lane * 2], tw1 = twp[lane * 2 + 1];
    float ob = tob[v];
    int cs[SPW];
#pragma unroll
    for (int s = 0; s < SPW; s++) cs[s] = w2s[v * SPW + s];
    uint4 rv[SPW];
#pragma unroll
    for (int s = 0; s < SPW; s++)
        rv[s] = ((const uint4*)(Rterm16 + (size_t)cs[s] * H_DIM))[lane];
    float d[SPW];
#pragma unroll
    for (int s = 0; s < SPW; s++) {
        d[s] = dot8_bf16(rv[s], tw0, tw1);
        d[s] += __shfl_xor(d[s], 1, 64);
        d[s] += __shfl_xor(d[s], 2, 64);
        d[s] += __shfl_xor(d[s], 4, 64);
    }
    float x = d[0];
    int myc = cs[0];
#pragma unroll
    for (int s = 1; s < SPW; s++) {
        if ((lane & 7) == s) { x = d[s]; myc = cs[s]; }
    }
    x += __shfl_xor(x, 8, 64);
    x += __shfl_xor(x, 16, 64);
    x += __shfl_xor(x, 32, 64);
    if (lane < 8)
        obs[idx * SPW + lane] = x + ob - logZ[myc];
}

// ---------------- log-semiring 8x8 matrix combine (lane = j*8+i) ----------------
__device__ __forceinline__ float lsm_combine(float accv, float mv, int i, int j)
{
    float x[8];
#pragma unroll
    for (int k = 0; k < 8; k++) {
        float a = __shfl(accv, k * 8 + i, 64);   // acc[i][k]
        float b = __shfl(mv,  j * 8 + k, 64);    // m[k][j]
        x[k] = a + b;
    }
    float mx = fmaxf(fmaxf(fmaxf(x[0], x[1]), fmaxf(x[2], x[3])),
                     fmaxf(fmaxf(x[4], x[5]), fmaxf(x[6], x[7])));
    float s = 0.0f;
#pragma unroll
    for (int k = 0; k < 8; k++) s += expf(x[k] - mx);
    return mx + logf(s);
}

// ---------------- fused potential + scan phase A --------------------------------
// Each wave folds 16 consecutive transition matrices, computing them on the fly:
// pot[t][j*8+i] = trans[ci(t,i)][cj(t+1,j)] + obs[b,t+1,j] (+ t==0 terms)
__global__ __launch_bounds__(256) void scanA_kern(
    const float* __restrict__ trans, const float* __restrict__ obs,
    const float* __restrict__ startv, const int* __restrict__ text,
    const int* __restrict__ w2s, float* __restrict__ Mc)
{
    int wid = threadIdx.x >> 6, lane = threadIdx.x & 63;
    int g = blockIdx.x * 4 + wid;        // 0 .. 255
    int b = g >> 4, c = g & 15;
    int t0 = c * 16;
    int cnt = min(16, (T_DIM - 1) - t0);
    int i = lane & 7, j = lane >> 3;

    const int* txt = text + b * T_DIM;
    const float* obsb = obs + (size_t)b * T_DIM * SPW;

    // pot(t) for transition t (t -> t+1)
    auto potval = [&](int t) -> float {
        int vt  = txt[t];
        int vt1 = txt[t + 1];
        int ci = w2s[vt * SPW + i];
        int cj = w2s[vt1 * SPW + j];
        float p = trans[(size_t)ci * C_DIM + cj] + obsb[(t + 1) * SPW + j];
        if (t == 0) p += startv[ci] + obsb[i];
        return p;
    };

    float acc = potval(t0);
    if (cnt > 1) {
        float nv = potval(t0 + 1);
        for (int t = t0 + 1; t < t0 + cnt; t++) {
            float nv2 = (t + 1 < t0 + cnt) ? potval(t + 1) : 0.0f;
            acc = lsm_combine(acc, nv, i, j);
            nv = nv2;
        }
    }
    Mc[(size_t)g * 64 + lane] = acc;
}

// ---------------- scan phase B: fold 16 chunk matrices, reduce to evidence ------
__global__ __launch_bounds__(64) void scanB_kern(const float* __restrict__ Mc,
                                                 float* __restrict__ evid)
{
    int b = blockIdx.x, lane = threadIdx.x;
    int i = lane & 7, j = lane >> 3;
    const float* base = Mc + (size_t)b * 16 * 64;
    float acc = base[lane];
    for (int c = 1; c < 16; c++)
        acc = lsm_combine(acc, base[(size_t)c * 64 + lane], i, j);
    float mx = acc;
    for (int o = 1; o < 64; o <<= 1) mx = fmaxf(mx, __shfl_xor(mx, o, 64));
    float e = expf(acc - mx);
    for (int o = 1; o < 64; o <<= 1) e += __shfl_xor(e, o, 64);
    if (lane == 0) atomicAdd(evid, mx + logf(e));
}

// ---------------- final scalar write (f32 out) ----------------------------------
__global__ void out_kern(const float* __restrict__ evid, float* __restrict__ out)
{
    if (threadIdx.x == 0) out[0] = *evid;
}

extern "C" void kernel_launch(void* const* d_in, const int* in_sizes, int n_in,
                              void* d_out, int out_size, void* d_ws, size_t ws_size,
                              hipStream_t stream)
{
    const float* start_emb = (const float*)d_in[0];
    const float* start_l1w = (const float*)d_in[1];
    const float* start_l1b = (const float*)d_in[2];
    const float* start_l2w = (const float*)d_in[3];
    const float* start_l2b = (const float*)d_in[4];
    const float* start_ow  = (const float*)d_in[5];
    const float* start_ob  = (const float*)d_in[6];
    const float* state_emb = (const float*)d_in[7];
    const float* trans_l1w = (const float*)d_in[8];
    const float* trans_l1b = (const float*)d_in[9];
    const float* trans_l2w = (const float*)d_in[10];
    const float* trans_l2b = (const float*)d_in[11];
    const float* proj_w    = (const float*)d_in[12];
    const float* pret_emb  = (const float*)d_in[13];
    const float* term_l1w  = (const float*)d_in[14];
    const float* term_l1b  = (const float*)d_in[15];
    const float* term_l2w  = (const float*)d_in[16];
    const float* term_l2b  = (const float*)d_in[17];
    const float* term_ow   = (const float*)d_in[18];
    const float* term_ob   = (const float*)d_in[19];
    const int*   text      = (const int*)d_in[20];
    const int*   w2s       = (const int*)d_in[21];

    char* w = (char*)d_ws;
    const u32 MB = 1u << 20;
    const size_t CH = (size_t)C_DIM * H_DIM;
    float* H3     = (float*)(w);                 // 6 MB (3x 1024x512)
    float* R3     = (float*)(w + 6u * MB);       // 6 MB (Rstart, Rtrans, [slot for bf16 Rterm])
    float* TL     = (float*)(w + 12u * MB);      // 4 MB
    float* startv = (float*)(w + 16u * MB);              // 4 KB
    float* logZ   = (float*)(w + 16u * MB + 8192);       // 4 KB
    float* obs    = (float*)(w + 16u * MB + 16384);      // 128 KB
    float* evid   = (float*)(w + 16u * MB + 16384 + 131072);
    float* Zpart  = (float*)(w + 16u * MB + 16384 + 131072 + 4096);   // 256 KB
    float* Mc     = (float*)(w + 16u * MB + 16384 + 131072 + 4096 + 262144); // 64 KB

    float* Hs = H3;
    float* Ht = H3 + CH;
    float* Hp = H3 + 2 * CH;
    float* Rstart = R3;
    float* Rtrans = R3 + CH;
    u16*   Rterm16 = (u16*)(R3 + 2 * CH);        // 1 MB bf16 in the third slot

    dim3 blk256(256), blk64(64);

    init_kern<<<NSLOT, 1024, 0, stream>>>(Zpart, evid);

    MlpArgs l1 = {{start_emb, state_emb, pret_emb},
                  {start_l1w, trans_l1w, term_l1w},
                  {start_l1b, trans_l1b, term_l1b},
                  {nullptr, nullptr, nullptr},
                  {Hs, Ht, Hp},
                  {nullptr, nullptr, nullptr}};
    MlpArgs l2 = {{Hs, Ht, Hp},
                  {start_l2w, trans_l2w, term_l2w},
                  {start_l2b, trans_l2b, term_l2b},
                  {start_emb, state_emb, pret_emb},
                  {Rstart, Rtrans, nullptr},
                  {nullptr, nullptr, Rterm16}};
    mlp_kern<<<dim3(16, 8, 3), blk256, 0, stream>>>(l1);
    mlp_kern<<<dim3(16, 8, 3), blk256, 0, stream>>>(l2);

    gemm_kern<<<dim3(16, 16), blk256, 0, stream>>>(Rtrans, proj_w, TL,
                                                   C_DIM, C_DIM, H_DIM);

    startlog_kern<<<C_DIM / 4, blk256, 0, stream>>>(Rstart, start_ow, start_ob, startv);
    startsm_kern<<<1, 1024, 0, stream>>>(startv);
    rowsm_kern<<<C_DIM, blk256, 0, stream>>>(TL);

    zsum_kern<<<V_DIM / 4, blk256, 0, stream>>>(Rterm16, term_ow, term_ob, w2s, Zpart);
    zred_kern<<<C_DIM / 256, blk256, 0, stream>>>(Zpart, logZ);
    obs_kern<<<B_DIM * T_DIM / 4, blk256, 0, stream>>>(Rterm16, term_ow, term_ob, w2s,
                                                       text, logZ, obs);

    scanA_kern<<<B_DIM * 16 / 4, blk256, 0, stream>>>(TL, obs, startv, text, w2s, Mc);
    scanB_kern<<<B_DIM, blk64, 0, stream>>>(Mc, evid);
    out_kern<<<1, 64, 0, stream>>>(evid, (float*)d_out);
}

// Round 8
// 240.576 us; speedup vs baseline: 2.5626x; 1.1724x over previous
//
#include <hip/hip_runtime.h>
#include <hip/hip_bf16.h>

#define C_DIM 1024
#define H_DIM 512
#define V_DIM 32000
#define B_DIM 16
#define T_DIM 256
#define SPW   8
#define NSLOT 32

typedef unsigned short u16;
typedef unsigned int   u32;
typedef __attribute__((ext_vector_type(8))) short bf16x8;
typedef __attribute__((ext_vector_type(4))) float f32x4;

__device__ __forceinline__ u16 f2b(float f) {
    union { float f; u32 i; } x; x.f = f;
    u32 i = x.i;
    i += 0x7fffu + ((i >> 16) & 1u);   // RNE
    return (u16)(i >> 16);
}
__device__ __forceinline__ float b2f(u16 u) {
    union { u32 i; float f; } x; x.i = ((u32)u) << 16; return x.f;
}
__device__ __forceinline__ float dot8_bf16(uint4 u, const float4 tw0, const float4 tw1) {
    return tw0.x * b2f((u16)(u.x & 0xffff)) + tw0.y * b2f((u16)(u.x >> 16))
         + tw0.z * b2f((u16)(u.y & 0xffff)) + tw0.w * b2f((u16)(u.y >> 16))
         + tw1.x * b2f((u16)(u.z & 0xffff)) + tw1.y * b2f((u16)(u.z >> 16))
         + tw1.z * b2f((u16)(u.w & 0xffff)) + tw1.w * b2f((u16)(u.w >> 16));
}

// ---------------- f32 -> bf16 convert (10 segments) + zero segment --------------
struct CvtArgs {
    const float* src[10];
    u16*         dst[10];
    int          n[10];      // element counts (multiples of 4)
    float*       zero;       // Zpart .. Ssum contiguous
    int          zn;
};

__global__ __launch_bounds__(256) void cvt_kern(CvtArgs a)
{
    int seg = blockIdx.y;
    if (seg == 10) {
        for (int i = blockIdx.x * 256 + threadIdx.x; i < a.zn; i += gridDim.x * 256)
            a.zero[i] = 0.0f;
        return;
    }
    const float4* s = (const float4*)a.src[seg];
    ushort4* d = (ushort4*)a.dst[seg];
    int n4 = a.n[seg] >> 2;
    for (int i = blockIdx.x * 256 + threadIdx.x; i < n4; i += gridDim.x * 256) {
        float4 v = s[i];
        ushort4 o;
        o.x = f2b(v.x); o.y = f2b(v.y); o.z = f2b(v.z); o.w = f2b(v.w);
        d[i] = o;
    }
}

// ---------------- batched bf16 MFMA MLP layer (3 problems via z) ----------------
// out16 = relu(A@W^T + bias) (+resid).  M=1024, N=512, K=512.
struct Mlp16Args {
    const u16*   A[3];
    const u16*   W[3];
    const float* bias[3];
    const u16*   resid[3];   // may be null
    u16*         out[3];
};

__global__ __launch_bounds__(256) void mlp16_kern(Mlp16Args args)
{
    const int N = H_DIM, K = H_DIM;
    int z = blockIdx.z;
    const u16* A = args.A[z];
    const u16* B = args.W[z];
    const float* bias = args.bias[z];
    const u16* resid = args.resid[z];
    u16* out = args.out[z];

    __shared__ __align__(16) u16 As[64][40];
    __shared__ __align__(16) u16 Bs[64][40];
    int tid  = threadIdx.x;
    int m0 = blockIdx.x * 64, n0 = blockIdx.y * 64;
    int wave = tid >> 6, lane = tid & 63;
    int wr = wave >> 1, wc = wave & 1;
    int srow = tid >> 2, scol = (tid & 3) << 3;
    int quad = lane >> 4, l16 = lane & 15;
    f32x4 acc[2][2] = {};

    for (int k0 = 0; k0 < K; k0 += 32) {
        uint4 av = *(const uint4*)(A + (size_t)(m0 + srow) * K + k0 + scol);
        uint4 bv = *(const uint4*)(B + (size_t)(n0 + srow) * K + k0 + scol);
        __syncthreads();
        *(uint4*)&As[srow][scol] = av;
        *(uint4*)&Bs[srow][scol] = bv;
        __syncthreads();
        bf16x8 af0 = *(const bf16x8*)&As[wr * 32 + l16][quad * 8];
        bf16x8 af1 = *(const bf16x8*)&As[wr * 32 + 16 + l16][quad * 8];
        bf16x8 bf0 = *(const bf16x8*)&Bs[wc * 32 + l16][quad * 8];
        bf16x8 bf1 = *(const bf16x8*)&Bs[wc * 32 + 16 + l16][quad * 8];
        acc[0][0] = __builtin_amdgcn_mfma_f32_16x16x32_bf16(af0, bf0, acc[0][0], 0, 0, 0);
        acc[0][1] = __builtin_amdgcn_mfma_f32_16x16x32_bf16(af0, bf1, acc[0][1], 0, 0, 0);
        acc[1][0] = __builtin_amdgcn_mfma_f32_16x16x32_bf16(af1, bf0, acc[1][0], 0, 0, 0);
        acc[1][1] = __builtin_amdgcn_mfma_f32_16x16x32_bf16(af1, bf1, acc[1][1], 0, 0, 0);
    }
#pragma unroll
    for (int sm = 0; sm < 2; sm++)
#pragma unroll
        for (int sn = 0; sn < 2; sn++) {
            int n = n0 + wc * 32 + sn * 16 + l16;
            float bv = bias[n];
#pragma unroll
            for (int reg = 0; reg < 4; reg++) {
                int m = m0 + wr * 32 + sm * 16 + quad * 4 + reg;
                float v = fmaxf(acc[sm][sn][reg] + bv, 0.0f);
                if (resid) v += b2f(resid[(size_t)m * N + n]);
                out[(size_t)m * N + n] = f2b(v);
            }
        }
}

// ---------------- bf16 GEMM, f32 out (trans logits) -----------------------------
__global__ __launch_bounds__(256) void gemm16_kern(
    const u16* __restrict__ A, const u16* __restrict__ B,
    float* __restrict__ out, int M, int N, int K)
{
    __shared__ __align__(16) u16 As[64][40];
    __shared__ __align__(16) u16 Bs[64][40];
    int tid  = threadIdx.x;
    int m0 = blockIdx.x * 64, n0 = blockIdx.y * 64;
    int wave = tid >> 6, lane = tid & 63;
    int wr = wave >> 1, wc = wave & 1;
    int srow = tid >> 2, scol = (tid & 3) << 3;
    int quad = lane >> 4, l16 = lane & 15;
    f32x4 acc[2][2] = {};

    for (int k0 = 0; k0 < K; k0 += 32) {
        uint4 av = *(const uint4*)(A + (size_t)(m0 + srow) * K + k0 + scol);
        uint4 bv = *(const uint4*)(B + (size_t)(n0 + srow) * K + k0 + scol);
        __syncthreads();
        *(uint4*)&As[srow][scol] = av;
        *(uint4*)&Bs[srow][scol] = bv;
        __syncthreads();
        bf16x8 af0 = *(const bf16x8*)&As[wr * 32 + l16][quad * 8];
        bf16x8 af1 = *(const bf16x8*)&As[wr * 32 + 16 + l16][quad * 8];
        bf16x8 bf0 = *(const bf16x8*)&Bs[wc * 32 + l16][quad * 8];
        bf16x8 bf1 = *(const bf16x8*)&Bs[wc * 32 + 16 + l16][quad * 8];
        acc[0][0] = __builtin_amdgcn_mfma_f32_16x16x32_bf16(af0, bf0, acc[0][0], 0, 0, 0);
        acc[0][1] = __builtin_amdgcn_mfma_f32_16x16x32_bf16(af0, bf1, acc[0][1], 0, 0, 0);
        acc[1][0] = __builtin_amdgcn_mfma_f32_16x16x32_bf16(af1, bf0, acc[1][0], 0, 0, 0);
        acc[1][1] = __builtin_amdgcn_mfma_f32_16x16x32_bf16(af1, bf1, acc[1][1], 0, 0, 0);
    }
#pragma unroll
    for (int sm = 0; sm < 2; sm++)
#pragma unroll
        for (int sn = 0; sn < 2; sn++) {
            int n = n0 + wc * 32 + sn * 16 + l16;
#pragma unroll
            for (int reg = 0; reg < 4; reg++) {
                int m = m0 + wr * 32 + sm * 16 + quad * 4 + reg;
                out[(size_t)m * N + n] = acc[sm][sn][reg];
            }
        }
}

// ---------------- start logits (raw) + slotted exp-sum --------------------------
__global__ __launch_bounds__(256) void startlog_kern(
    const u16* __restrict__ Rstart16, const float* __restrict__ sow,
    const float* __restrict__ sob, float* __restrict__ startv,
    float* __restrict__ Ssum)
{
    int wid = threadIdx.x >> 6, lane = threadIdx.x & 63;
    int c = blockIdx.x * 4 + wid;
    uint4 rv = ((const uint4*)(Rstart16 + (size_t)c * H_DIM))[lane];
    const float4* wp = (const float4*)(sow);
    float4 w0 = wp[lane * 2], w1 = wp[lane * 2 + 1];
    float d = dot8_bf16(rv, w0, w1);
    for (int off = 1; off < 64; off <<= 1) d += __shfl_xor(d, off, 64);
    if (lane == 0) {
        d += sob[0];
        startv[c] = d;
        atomicAdd(Ssum + (blockIdx.x & (NSLOT - 1)), expf(d));
    }
}

// ---------------- row lse of TL (no rewrite): rowlse[r] = log sum exp -----------
__global__ __launch_bounds__(256) void rowlse_kern(const float* __restrict__ TL,
                                                   float* __restrict__ rowlse)
{
    int wid = threadIdx.x >> 6, lane = threadIdx.x & 63;
    int row = blockIdx.x * 4 + wid;
    const float4* p = (const float4*)(TL + (size_t)row * C_DIM);
    float s = 0.0f;
#pragma unroll
    for (int k = 0; k < 4; k++) {
        float4 v = p[lane + 64 * k];
        s += expf(v.x) + expf(v.y) + expf(v.z) + expf(v.w);
    }
    for (int off = 1; off < 64; off <<= 1) s += __shfl_xor(s, off, 64);
    if (lane == 0) rowlse[row] = logf(s);
}

// ---------------- emission denominator: bf16 gather, slotted atomics ------------
__global__ __launch_bounds__(256) void zsum_kern(
    const u16* __restrict__ Rterm16, const float* __restrict__ tow,
    const float* __restrict__ tob, const int* __restrict__ w2s,
    float* __restrict__ Zpart)
{
    int wid = threadIdx.x >> 6, lane = threadIdx.x & 63;
    int v = blockIdx.x * 4 + wid;
    float* slot = Zpart + (blockIdx.x & (NSLOT - 1)) * C_DIM;
    const float4* twp = (const float4*)(tow + (size_t)v * H_DIM);
    float4 tw0 = twp[lane * 2], tw1 = twp[lane * 2 + 1];
    float ob = tob[v];
    int cs[SPW];
#pragma unroll
    for (int s = 0; s < SPW; s++) cs[s] = w2s[v * SPW + s];
    uint4 rv[SPW];
#pragma unroll
    for (int s = 0; s < SPW; s++)
        rv[s] = ((const uint4*)(Rterm16 + (size_t)cs[s] * H_DIM))[lane];
    float d[SPW];
#pragma unroll
    for (int s = 0; s < SPW; s++) {
        d[s] = dot8_bf16(rv[s], tw0, tw1);
        d[s] += __shfl_xor(d[s], 1, 64);
        d[s] += __shfl_xor(d[s], 2, 64);
        d[s] += __shfl_xor(d[s], 4, 64);
    }
    float x = d[0];
    int myc = cs[0];
#pragma unroll
    for (int s = 1; s < SPW; s++) {
        if ((lane & 7) == s) { x = d[s]; myc = cs[s]; }
    }
    x += __shfl_xor(x, 8, 64);
    x += __shfl_xor(x, 16, 64);
    x += __shfl_xor(x, 32, 64);
    u32 dupmask = 0;
#pragma unroll
    for (int s = 1; s < SPW; s++) {
        bool dp = false;
#pragma unroll
        for (int s2 = 0; s2 < s; s2++) dp = dp || (cs[s2] == cs[s]);
        if (dp) dupmask |= (1u << s);
    }
    if (lane < 8 && !((dupmask >> lane) & 1u))
        atomicAdd(slot + myc, expf(x + ob));
}

// ---------------- obs[b,t,s] = term_logit - logZ (zred folded in) ---------------
__global__ __launch_bounds__(256) void obs_kern(
    const u16* __restrict__ Rterm16, const float* __restrict__ tow,
    const float* __restrict__ tob, const int* __restrict__ w2s,
    const int* __restrict__ text, const float* __restrict__ Zpart,
    float* __restrict__ obs)
{
    int wid = threadIdx.x >> 6, lane = threadIdx.x & 63;
    int idx = blockIdx.x * 4 + wid;          // 0 .. B*T-1
    int v = text[idx];
    const float4* twp = (const float4*)(tow + (size_t)v * H_DIM);
    float4 tw0 = twp[lane * 2], tw1 = twp[lane * 2 + 1];
    float ob = tob[v];
    int cs[SPW];
#pragma unroll
    for (int s = 0; s < SPW; s++) cs[s] = w2s[v * SPW + s];
    uint4 rv[SPW];
#pragma unroll
    for (int s = 0; s < SPW; s++)
        rv[s] = ((const uint4*)(Rterm16 + (size_t)cs[s] * H_DIM))[lane];
    float d[SPW];
#pragma unroll
    for (int s = 0; s < SPW; s++) {
        d[s] = dot8_bf16(rv[s], tw0, tw1);
        d[s] += __shfl_xor(d[s], 1, 64);
        d[s] += __shfl_xor(d[s], 2, 64);
        d[s] += __shfl_xor(d[s], 4, 64);
    }
    float x = d[0];
    int myc = cs[0];
#pragma unroll
    for (int s = 1; s < SPW; s++) {
        if ((lane & 7) == s) { x = d[s]; myc = cs[s]; }
    }
    x += __shfl_xor(x, 8, 64);
    x += __shfl_xor(x, 16, 64);
    x += __shfl_xor(x, 32, 64);
    // fold zred: sum Zpart slots for state myc; lane group g handles 4 slots
    int g = lane >> 3;
    float zp = 0.0f;
#pragma unroll
    for (int k = 0; k < 4; k++)
        zp += Zpart[(size_t)(g * 4 + k) * C_DIM + myc];
    zp += __shfl_xor(zp, 8, 64);
    zp += __shfl_xor(zp, 16, 64);
    zp += __shfl_xor(zp, 32, 64);
    if (lane < 8)
        obs[idx * SPW + lane] = x + ob - logf(zp);
}

// ---------------- log-semiring 8x8 matrix combine (lane = j*8+i) ----------------
__device__ __forceinline__ float lsm_combine(float accv, float mv, int i, int j)
{
    float x[8];
#pragma unroll
    for (int k = 0; k < 8; k++) {
        float a = __shfl(accv, k * 8 + i, 64);   // acc[i][k]
        float b = __shfl(mv,  j * 8 + k, 64);    // m[k][j]
        x[k] = a + b;
    }
    float mx = fmaxf(fmaxf(fmaxf(x[0], x[1]), fmaxf(x[2], x[3])),
                     fmaxf(fmaxf(x[4], x[5]), fmaxf(x[6], x[7])));
    float s = 0.0f;
#pragma unroll
    for (int k = 0; k < 8; k++) s += expf(x[k] - mx);
    return mx + logf(s);
}

// ---------------- fused potential + scan phase A --------------------------------
__global__ __launch_bounds__(256) void scanA_kern(
    const float* __restrict__ TL, const float* __restrict__ rowlse,
    const float* __restrict__ obs, const float* __restrict__ startv,
    const float* __restrict__ Ssum, const int* __restrict__ text,
    const int* __restrict__ w2s, float* __restrict__ Mc)
{
    int wid = threadIdx.x >> 6, lane = threadIdx.x & 63;
    int g = blockIdx.x * 4 + wid;        // 0 .. 255
    int b = g >> 4, c = g & 15;
    int t0 = c * 16;
    int cnt = min(16, (T_DIM - 1) - t0);
    int i = lane & 7, j = lane >> 3;

    const int* txt = text + b * T_DIM;
    const float* obsb = obs + (size_t)b * T_DIM * SPW;

    float logS = 0.0f;
    if (t0 == 0) {
        float ss = 0.0f;
#pragma unroll
        for (int k = 0; k < NSLOT; k++) ss += Ssum[k];
        logS = logf(ss);
    }

    auto potval = [&](int t) -> float {
        int vt  = txt[t];
        int vt1 = txt[t + 1];
        int ci = w2s[vt * SPW + i];
        int cj = w2s[vt1 * SPW + j];
        float p = TL[(size_t)ci * C_DIM + cj] - rowlse[ci] + obsb[(t + 1) * SPW + j];
        if (t == 0) p += startv[ci] - logS + obsb[i];
        return p;
    };

    float acc = potval(t0);
    if (cnt > 1) {
        float nv = potval(t0 + 1);
        for (int t = t0 + 1; t < t0 + cnt; t++) {
            float nv2 = (t + 1 < t0 + cnt) ? potval(t + 1) : 0.0f;
            acc = lsm_combine(acc, nv, i, j);
            nv = nv2;
        }
    }
    Mc[(size_t)g * 64 + lane] = acc;
}

// ---------------- scan phase B: 16 waves (one per batch), writes d_out ----------
__global__ __launch_bounds__(1024) void scanB_kern(const float* __restrict__ Mc,
                                                   float* __restrict__ out)
{
    int wave = threadIdx.x >> 6, lane = threadIdx.x & 63;
    int i = lane & 7, j = lane >> 3;
    const float* base = Mc + (size_t)wave * 16 * 64;
    float acc = base[lane];
    for (int c = 1; c < 16; c++)
        acc = lsm_combine(acc, base[(size_t)c * 64 + lane], i, j);
    float mx = acc;
    for (int o = 1; o < 64; o <<= 1) mx = fmaxf(mx, __shfl_xor(mx, o, 64));
    float e = expf(acc - mx);
    for (int o = 1; o < 64; o <<= 1) e += __shfl_xor(e, o, 64);
    __shared__ float part[16];
    if (lane == 0) part[wave] = mx + logf(e);
    __syncthreads();
    if (threadIdx.x == 0) {
        float s = 0.0f;
#pragma unroll
        for (int k = 0; k < 16; k++) s += part[k];
        out[0] = s;
    }
}

extern "C" void kernel_launch(void* const* d_in, const int* in_sizes, int n_in,
                              void* d_out, int out_size, void* d_ws, size_t ws_size,
                              hipStream_t stream)
{
    const float* start_emb = (const float*)d_in[0];
    const float* start_l1w = (const float*)d_in[1];
    const float* start_l1b = (const float*)d_in[2];
    const float* start_l2w = (const float*)d_in[3];
    const float* start_l2b = (const float*)d_in[4];
    const float* start_ow  = (const float*)d_in[5];
    const float* start_ob  = (const float*)d_in[6];
    const float* state_emb = (const float*)d_in[7];
    const float* trans_l1w = (const float*)d_in[8];
    const float* trans_l1b = (const float*)d_in[9];
    const float* trans_l2w = (const float*)d_in[10];
    const float* trans_l2b = (const float*)d_in[11];
    const float* proj_w    = (const float*)d_in[12];
    const float* pret_emb  = (const float*)d_in[13];
    const float* term_l1w  = (const float*)d_in[14];
    const float* term_l1b  = (const float*)d_in[15];
    const float* term_l2w  = (const float*)d_in[16];
    const float* term_l2b  = (const float*)d_in[17];
    const float* term_ow   = (const float*)d_in[18];
    const float* term_ob   = (const float*)d_in[19];
    const int*   text      = (const int*)d_in[20];
    const int*   w2s       = (const int*)d_in[21];

    char* w = (char*)d_ws;
    const u32 MB = 1u << 20;
    const size_t CH = (size_t)C_DIM * H_DIM;   // 524288
    const size_t HH = (size_t)H_DIM * H_DIM;   // 262144

    // bf16 buffers
    u16* emb16   = (u16*)(w);                        // 3 MB: start/state/pret emb
    u16* w16     = (u16*)(w + 3u * MB);              // 3 MB: 6 weights of 512KB
    u16* proj16  = (u16*)(w + 6u * MB);              // 1 MB
    u16* H16     = (u16*)(w + 7u * MB);              // 3 MB: hidden x3
    u16* R16     = (u16*)(w + 10u * MB);             // 3 MB: Rstart/Rtrans/Rterm
    float* TL    = (float*)(w + 13u * MB);           // 4 MB
    float* startv  = (float*)(w + 17u * MB);                 // 4 KB
    float* rowlse  = (float*)(w + 17u * MB + 4096);          // 4 KB
    float* obs     = (float*)(w + 17u * MB + 8192);          // 128 KB
    float* Mc      = (float*)(w + 17u * MB + 8192 + 131072); // 64 KB
    float* Zpart   = (float*)(w + 18u * MB);                 // 128 KB
    float* Ssum    = Zpart + (size_t)NSLOT * C_DIM;          // 32 floats (contiguous)

    u16* semb16 = emb16;
    u16* temb16 = emb16 + CH;
    u16* pemb16 = emb16 + 2 * CH;
    u16* sl1w16 = w16;
    u16* sl2w16 = w16 + HH;
    u16* tl1w16 = w16 + 2 * HH;
    u16* tl2w16 = w16 + 3 * HH;
    u16* ml1w16 = w16 + 4 * HH;
    u16* ml2w16 = w16 + 5 * HH;
    u16* Hs = H16, *Ht = H16 + CH, *Hp = H16 + 2 * CH;
    u16* Rstart16 = R16;
    u16* Rtrans16 = R16 + CH;
    u16* Rterm16  = R16 + 2 * CH;

    dim3 blk256(256);

    CvtArgs cv;
    cv.src[0] = start_emb; cv.dst[0] = semb16; cv.n[0] = (int)CH;
    cv.src[1] = state_emb; cv.dst[1] = temb16; cv.n[1] = (int)CH;
    cv.src[2] = pret_emb;  cv.dst[2] = pemb16; cv.n[2] = (int)CH;
    cv.src[3] = start_l1w; cv.dst[3] = sl1w16; cv.n[3] = (int)HH;
    cv.src[4] = start_l2w; cv.dst[4] = sl2w16; cv.n[4] = (int)HH;
    cv.src[5] = trans_l1w; cv.dst[5] = tl1w16; cv.n[5] = (int)HH;
    cv.src[6] = trans_l2w; cv.dst[6] = tl2w16; cv.n[6] = (int)HH;
    cv.src[7] = term_l1w;  cv.dst[7] = ml1w16; cv.n[7] = (int)HH;
    cv.src[8] = term_l2w;  cv.dst[8] = ml2w16; cv.n[8] = (int)HH;
    cv.src[9] = proj_w;    cv.dst[9] = proj16; cv.n[9] = (int)CH;
    cv.zero = Zpart; cv.zn = NSLOT * C_DIM + NSLOT;
    cvt_kern<<<dim3(128, 11), blk256, 0, stream>>>(cv);

    Mlp16Args l1 = {{semb16, temb16, pemb16},
                    {sl1w16, tl1w16, ml1w16},
                    {start_l1b, trans_l1b, term_l1b},
                    {nullptr, nullptr, nullptr},
                    {Hs, Ht, Hp}};
    Mlp16Args l2 = {{Hs, Ht, Hp},
                    {sl2w16, tl2w16, ml2w16},
                    {start_l2b, trans_l2b, term_l2b},
                    {semb16, temb16, pemb16},
                    {Rstart16, Rtrans16, Rterm16}};
    mlp16_kern<<<dim3(16, 8, 3), blk256, 0, stream>>>(l1);
    mlp16_kern<<<dim3(16, 8, 3), blk256, 0, stream>>>(l2);

    gemm16_kern<<<dim3(16, 16), blk256, 0, stream>>>(Rtrans16, proj16, TL,
                                                     C_DIM, C_DIM, H_DIM);

    startlog_kern<<<C_DIM / 4, blk256, 0, stream>>>(Rstart16, start_ow, start_ob,
                                                    startv, Ssum);
    zsum_kern<<<V_DIM / 4, blk256, 0, stream>>>(Rterm16, term_ow, term_ob, w2s, Zpart);
    rowlse_kern<<<C_DIM / 4, blk256, 0, stream>>>(TL, rowlse);
    obs_kern<<<B_DIM * T_DIM / 4, blk256, 0, stream>>>(Rterm16, term_ow, term_ob, w2s,
                                                       text, Zpart, obs);
    scanA_kern<<<B_DIM * 16 / 4, blk256, 0, stream>>>(TL, rowlse, obs, startv, Ssum,
                                                      text, w2s, Mc);
    scanB_kern<<<1, 1024, 0, stream>>>(Mc, (float*)d_out);
}